// Round 1
// baseline (924.171 us; speedup 1.0000x reference)
//
#include <hip/hip_runtime.h>

#define B_SZ 1024
#define N_SZ 64
#define C_SZ 256
#define H_SZ 8
#define HD_SZ 32

// regA float layout:
//  phase1: xs[64*32] @0, wqs[32*32] @2048, wks[32*32] @3072, wvs[32*32] @4096 (5120 floats)
//  phase3/4: As[64*65] @0 (4160), ua[64*33] @4160, ub[64*33] @6272  (8384 floats total)
#define REGA_FLOATS 8384

__global__ __launch_bounds__(256) void attn_kernel(
    const float* __restrict__ x,          // [B,N,C]
    const float* __restrict__ Wq,         // [C,C]
    const float* __restrict__ bq,         // [C]
    const float* __restrict__ Wkv,        // [C,2C]
    const float* __restrict__ bkv,        // [2C]
    const float* __restrict__ Wgate,      // [HD,4]
    const float* __restrict__ bgate,      // [4]
    const float* __restrict__ bias_table, // [225,H]
    const int*   __restrict__ rel_index,  // [N,N]
    float* __restrict__ hidden)           // [B,N,C]
{
    __shared__ float regA[REGA_FLOATS];
    __shared__ float qs[64][33];
    __shared__ float ks[64][33];
    __shared__ float vs[64][33];
    __shared__ float msum[32];
    __shared__ float gw[4];
    __shared__ float dnv[64];

    const int bh = blockIdx.x;
    const int b  = bh >> 3;
    const int h  = bh & 7;
    const int t  = threadIdx.x;
    const int d  = t & 31;   // head-dim column 0..31
    const int rg = t >> 5;   // row group 0..7 (8 rows each)

    float* xs  = regA;
    float* wqs = regA + 2048;
    float* wks = regA + 3072;
    float* wvs = regA + 4096;

    // ---- phase 1: q/k/v = x[b] @ {Wq,Wk,Wv}[:, h-slice] + bias, accumulated in regs ----
    float accq[8], acck[8], accv[8];
    {
        const float bqv  = bq[h*HD_SZ + d];
        const float bkv_ = bkv[h*HD_SZ + d];
        const float bvv  = bkv[C_SZ + h*HD_SZ + d];
        #pragma unroll
        for (int r = 0; r < 8; r++) { accq[r] = bqv; acck[r] = bkv_; accv[r] = bvv; }
    }

    const float* xb = x + (size_t)b * N_SZ * C_SZ;

    for (int kc = 0; kc < C_SZ; kc += 32) {
        // stage x chunk [64 rows][32 cols] (float4 coalesced)
        #pragma unroll
        for (int i = 0; i < 2; i++) {
            int f4  = t + i * 256;
            int row = f4 >> 3;
            int c4  = (f4 & 7) * 4;
            *reinterpret_cast<float4*>(&xs[row*32 + c4]) =
                *reinterpret_cast<const float4*>(&xb[row*C_SZ + kc + c4]);
        }
        // stage weight chunks [32 kk][32 d]
        {
            int kk = t >> 3;
            int d4 = (t & 7) * 4;
            *reinterpret_cast<float4*>(&wqs[kk*32 + d4]) =
                *reinterpret_cast<const float4*>(&Wq[(size_t)(kc+kk)*C_SZ + h*HD_SZ + d4]);
            *reinterpret_cast<float4*>(&wks[kk*32 + d4]) =
                *reinterpret_cast<const float4*>(&Wkv[(size_t)(kc+kk)*2*C_SZ + h*HD_SZ + d4]);
            *reinterpret_cast<float4*>(&wvs[kk*32 + d4]) =
                *reinterpret_cast<const float4*>(&Wkv[(size_t)(kc+kk)*2*C_SZ + C_SZ + h*HD_SZ + d4]);
        }
        __syncthreads();

        // fused gate input: column means of x[b] restricted to this head's 32 channels
        if (kc == h*HD_SZ && t < 32) {
            float s = 0.0f;
            for (int m = 0; m < 64; m++) s += xs[m*32 + t];
            msum[t] = s * (1.0f/64.0f);
        }

        for (int kk = 0; kk < 32; kk += 4) {
            float wq0 = wqs[(kk+0)*32 + d], wq1 = wqs[(kk+1)*32 + d],
                  wq2 = wqs[(kk+2)*32 + d], wq3 = wqs[(kk+3)*32 + d];
            float wk0 = wks[(kk+0)*32 + d], wk1 = wks[(kk+1)*32 + d],
                  wk2 = wks[(kk+2)*32 + d], wk3 = wks[(kk+3)*32 + d];
            float wv0 = wvs[(kk+0)*32 + d], wv1 = wvs[(kk+1)*32 + d],
                  wv2 = wvs[(kk+2)*32 + d], wv3 = wvs[(kk+3)*32 + d];
            #pragma unroll
            for (int r = 0; r < 8; r++) {
                float4 x4 = *reinterpret_cast<const float4*>(&xs[(rg*8 + r)*32 + kk]);
                accq[r] = fmaf(x4.x, wq0, accq[r]);
                accq[r] = fmaf(x4.y, wq1, accq[r]);
                accq[r] = fmaf(x4.z, wq2, accq[r]);
                accq[r] = fmaf(x4.w, wq3, accq[r]);
                acck[r] = fmaf(x4.x, wk0, acck[r]);
                acck[r] = fmaf(x4.y, wk1, acck[r]);
                acck[r] = fmaf(x4.z, wk2, acck[r]);
                acck[r] = fmaf(x4.w, wk3, acck[r]);
                accv[r] = fmaf(x4.x, wv0, accv[r]);
                accv[r] = fmaf(x4.y, wv1, accv[r]);
                accv[r] = fmaf(x4.z, wv2, accv[r]);
                accv[r] = fmaf(x4.w, wv3, accv[r]);
            }
        }
        __syncthreads();
    }

    // ---- phase 2: spill q/k/v to LDS tiles, softmax rows, gate sigmoid ----
    #pragma unroll
    for (int r = 0; r < 8; r++) {
        int m = rg*8 + r;
        qs[m][d] = accq[r];
        ks[m][d] = acck[r];
        vs[m][d] = accv[r];
    }
    __syncthreads();

    if (t < 128) {
        float* row = (t < 64) ? &qs[t][0] : &ks[t-64][0];
        float mx = row[0];
        for (int j = 1; j < 32; j++) mx = fmaxf(mx, row[j]);
        float s = 0.0f;
        for (int j = 0; j < 32; j++) { float e = __expf(row[j] - mx); row[j] = e; s += e; }
        float inv = 1.0f / s;
        for (int j = 0; j < 32; j++) row[j] *= inv;
    } else if (t < 132) {
        int j = t - 128;
        float s = bgate[j];
        for (int dd = 0; dd < 32; dd++) s = fmaf(msum[dd], Wgate[dd*4 + j], s);
        gw[j] = 1.0f / (1.0f + __expf(-s));
    }
    __syncthreads();

    // polynomial weights from gates (single thread; gw re-read well after later barriers)
    if (t == 0) {
        float g0 = gw[0], g1 = gw[1], g2 = gw[2], g3 = gw[3];
        float a  = 0.125f*g3, bb = 0.375f*g0, cc = 0.375f*g1, dd = 0.125f*g2;
        gw[0] = a + bb + cc + dd;
        gw[1] = 3.0f*a + bb - cc - 3.0f*dd;
        gw[2] = 3.0f*a - bb - cc + 3.0f*dd;
        gw[3] = a - bb + cc - dd;
    }

    // ---- phase 3: S = q k^T + relu(bias) -> As[64][65] (reuses regA) ----
    float* As = regA;
    {
        const int tx = t & 15, ty = t >> 4;
        const int i0 = ty*4, j0 = tx*4;
        float acc[4][4] = {};
        for (int dd = 0; dd < 32; dd++) {
            float qv[4], kv4[4];
            #pragma unroll
            for (int ii = 0; ii < 4; ii++) qv[ii]  = qs[i0+ii][dd];
            #pragma unroll
            for (int jj = 0; jj < 4; jj++) kv4[jj] = ks[j0+jj][dd];
            #pragma unroll
            for (int ii = 0; ii < 4; ii++)
                #pragma unroll
                for (int jj = 0; jj < 4; jj++)
                    acc[ii][jj] = fmaf(qv[ii], kv4[jj], acc[ii][jj]);
        }
        #pragma unroll
        for (int ii = 0; ii < 4; ii++)
            #pragma unroll
            for (int jj = 0; jj < 4; jj++) {
                int i = i0 + ii, j = j0 + jj;
                float bias = bias_table[(size_t)rel_index[i*64 + j]*H_SZ + h];
                As[i*65 + j] = acc[ii][jj] + fmaxf(bias, 0.0f);
            }
    }
    __syncthreads();

    // symmetrize (read-all, barrier, write-all)
    {
        const int j  = t & 63;
        const int i0 = (t >> 6) * 16;
        float sij[16], sji[16];
        #pragma unroll
        for (int r = 0; r < 16; r++) {
            int i = i0 + r;
            sij[r] = As[i*65 + j];
            sji[r] = As[j*65 + i];
        }
        __syncthreads();
        #pragma unroll
        for (int r = 0; r < 16; r++) {
            int i = i0 + r;
            As[i*65 + j] = 0.5f * (sij[r] + sji[r]);
        }
    }
    __syncthreads();

    // degrees + D^{-1/2} A D^{-1/2}
    if (t < 64) {
        float s = 0.0f;
        for (int j = 0; j < 64; j++) s += As[t*65 + j];
        dnv[t] = (s > 0.0f) ? (1.0f / sqrtf(s)) : s;
    }
    __syncthreads();
    {
        const int j  = t & 63;
        const int i0 = (t >> 6) * 16;
        const float dj = dnv[j];
        #pragma unroll
        for (int r = 0; r < 16; r++) {
            int i = i0 + r;
            As[i*65 + j] *= dnv[i] * dj;
        }
    }
    __syncthreads();

    // ---- phase 4: y = (w0 I + w1 A + w2 A^2 + w3 A^3) v ----
    float* ua = regA + 4160;
    float* ub = regA + 6272;
    const float w0 = gw[0], w1 = gw[1], w2 = gw[2], w3 = gw[3];
    float y[8];
    #pragma unroll
    for (int r = 0; r < 8; r++) y[r] = w0 * vs[rg*8 + r][d];

    { // u1 = A v
        float s[8] = {};
        for (int j = 0; j < 64; j++) {
            float u = vs[j][d];
            #pragma unroll
            for (int r = 0; r < 8; r++) s[r] = fmaf(As[(rg*8 + r)*65 + j], u, s[r]);
        }
        #pragma unroll
        for (int r = 0; r < 8; r++) { ua[(rg*8 + r)*33 + d] = s[r]; y[r] = fmaf(w1, s[r], y[r]); }
    }
    __syncthreads();
    { // u2 = A u1
        float s[8] = {};
        for (int j = 0; j < 64; j++) {
            float u = ua[j*33 + d];
            #pragma unroll
            for (int r = 0; r < 8; r++) s[r] = fmaf(As[(rg*8 + r)*65 + j], u, s[r]);
        }
        #pragma unroll
        for (int r = 0; r < 8; r++) { ub[(rg*8 + r)*33 + d] = s[r]; y[r] = fmaf(w2, s[r], y[r]); }
    }
    __syncthreads();
    { // u3 = A u2
        float s[8] = {};
        for (int j = 0; j < 64; j++) {
            float u = ub[j*33 + d];
            #pragma unroll
            for (int r = 0; r < 8; r++) s[r] = fmaf(As[(rg*8 + r)*65 + j], u, s[r]);
        }
        #pragma unroll
        for (int r = 0; r < 8; r++) y[r] = fmaf(w3, s[r], y[r]);
    }

    // write hidden[b, n, h*32+d]
    float* hb = hidden + (size_t)b * N_SZ * C_SZ + h*HD_SZ + d;
    #pragma unroll
    for (int r = 0; r < 8; r++) hb[(size_t)(rg*8 + r) * C_SZ] = y[r];
}

// out = hidden @ Wproj + bproj   (M=65536, N=256, K=256)
__global__ __launch_bounds__(256) void proj_kernel(
    const float* __restrict__ hidden,
    const float* __restrict__ Wproj,
    const float* __restrict__ bproj,
    float* __restrict__ out)
{
    __shared__ float Asm[64][65];
    __shared__ float Bsm[64][65];

    const int rb = blockIdx.x;   // 0..1023 (rows of 64)
    const int cb = blockIdx.y;   // 0..3    (cols of 64)
    const int t  = threadIdx.x;
    const int tx = t & 15, ty = t >> 4;

    float acc[4][4] = {};

    for (int kc = 0; kc < 256; kc += 64) {
        #pragma unroll
        for (int i = 0; i < 4; i++) {
            int f4  = t + i * 256;
            int row = f4 >> 4;
            int c4  = (f4 & 15) * 4;
            *reinterpret_cast<float4*>(&Asm[row][c4]) =
                *reinterpret_cast<const float4*>(&hidden[(size_t)(rb*64+row)*256 + kc + c4]);
            *reinterpret_cast<float4*>(&Bsm[row][c4]) =
                *reinterpret_cast<const float4*>(&Wproj[(size_t)(kc+row)*256 + cb*64 + c4]);
        }
        __syncthreads();

        for (int kk = 0; kk < 64; kk++) {
            float a[4], bb[4];
            #pragma unroll
            for (int i = 0; i < 4; i++) a[i]  = Asm[ty*4+i][kk];
            #pragma unroll
            for (int j = 0; j < 4; j++) bb[j] = Bsm[kk][tx*4+j];
            #pragma unroll
            for (int i = 0; i < 4; i++)
                #pragma unroll
                for (int j = 0; j < 4; j++)
                    acc[i][j] = fmaf(a[i], bb[j], acc[i][j]);
        }
        __syncthreads();
    }

    #pragma unroll
    for (int i = 0; i < 4; i++) {
        int row = rb*64 + ty*4 + i;
        int col = cb*64 + tx*4;
        float4 o;
        o.x = acc[i][0] + bproj[col+0];
        o.y = acc[i][1] + bproj[col+1];
        o.z = acc[i][2] + bproj[col+2];
        o.w = acc[i][3] + bproj[col+3];
        *reinterpret_cast<float4*>(&out[(size_t)row*256 + col]) = o;
    }
}

extern "C" void kernel_launch(void* const* d_in, const int* in_sizes, int n_in,
                              void* d_out, int out_size, void* d_ws, size_t ws_size,
                              hipStream_t stream) {
    const float* x          = (const float*)d_in[0];
    const float* Wq         = (const float*)d_in[1];
    const float* bq         = (const float*)d_in[2];
    const float* Wkv        = (const float*)d_in[3];
    const float* bkv        = (const float*)d_in[4];
    const float* Wgate      = (const float*)d_in[5];
    const float* bgate      = (const float*)d_in[6];
    const float* Wproj      = (const float*)d_in[7];
    const float* bproj      = (const float*)d_in[8];
    const float* bias_table = (const float*)d_in[9];
    const int*   rel_index  = (const int*)d_in[10];
    float* out    = (float*)d_out;
    float* hidden = (float*)d_ws;   // 64 MB scratch: [B,N,C] f32

    attn_kernel<<<dim3(B_SZ * H_SZ), dim3(256), 0, stream>>>(
        x, Wq, bq, Wkv, bkv, Wgate, bgate, bias_table, rel_index, hidden);
    proj_kernel<<<dim3(B_SZ * N_SZ / 64, C_SZ / 64), dim3(256), 0, stream>>>(
        hidden, Wproj, bproj, out);
}

// Round 2
// 323.206 us; speedup vs baseline: 2.8594x; 2.8594x over previous
//
#include <hip/hip_runtime.h>

typedef __attribute__((ext_vector_type(8))) short bf16x8;
typedef __attribute__((ext_vector_type(4))) float f32x4;

// ---- workspace byte offsets ----
#define WS_HID    0u           // hidden bf16 [1024*64][256]  (33,554,432 B)
#define WS_WQ     33554432u    // Wq^T  bf16 [256 out][256 k]
#define WS_WK     33685504u    // Wk^T  bf16
#define WS_WV     33816576u    // Wv^T  bf16
#define WS_WP     33947648u    // Wproj^T bf16
#define WS_BIAS   34078720u    // relu(bias) f32 [8][64][64]
#define WS_XMEAN  34209792u    // x col-means f32 [1024][256]

__device__ __forceinline__ unsigned short f2bf(float f) {
    unsigned int u = __float_as_uint(f);
    u += 0x7FFFu + ((u >> 16) & 1u);   // RNE
    return (unsigned short)(u >> 16);
}
__device__ __forceinline__ unsigned int pk2(float lo, float hi) {
    return (unsigned int)f2bf(lo) | ((unsigned int)f2bf(hi) << 16);
}
__device__ __forceinline__ bf16x8 as_bf(uint4 u) {
    union { uint4 a; bf16x8 b; } c; c.a = u; return c.b;
}

// ===================== prep =====================
__global__ __launch_bounds__(256) void prep_kernel(
    const float* __restrict__ x, const float* __restrict__ Wq,
    const float* __restrict__ Wkv, const float* __restrict__ Wproj,
    const float* __restrict__ bias_table, const int* __restrict__ rel_index,
    unsigned char* __restrict__ ws)
{
    const int bid = blockIdx.x, t = threadIdx.x;
    if (bid < 1024) {
        // column means of x[b] over N=64
        float s = 0.f;
        const float* xb = x + (size_t)bid * 16384 + t;
        #pragma unroll 8
        for (int n = 0; n < 64; n++) s += xb[n * 256];
        ((float*)(ws + WS_XMEAN))[bid * 256 + t] = s * (1.f / 64.f);
    } else if (bid < 2048) {
        // transpose-pack 4 weight matrices to bf16: dst[o][k] = src[k][o]
        int e = (bid - 1024) * 256 + t;
        int m = e >> 16, r = e & 65535, o = r >> 8, kk = r & 255;
        float v; unsigned short* dst;
        if (m == 0)      { v = Wq[kk * 256 + o];         dst = (unsigned short*)(ws + WS_WQ); }
        else if (m == 1) { v = Wkv[kk * 512 + o];        dst = (unsigned short*)(ws + WS_WK); }
        else if (m == 2) { v = Wkv[kk * 512 + 256 + o];  dst = (unsigned short*)(ws + WS_WV); }
        else             { v = Wproj[kk * 256 + o];      dst = (unsigned short*)(ws + WS_WP); }
        dst[o * 256 + kk] = f2bf(v);
    } else {
        // pre-relu positional bias: [h][i*64+j]
        int e = (bid - 2048) * 256 + t;
        int hh = e >> 12, ij = e & 4095;
        ((float*)(ws + WS_BIAS))[hh * 4096 + ij] = fmaxf(bias_table[rel_index[ij] * 8 + hh], 0.f);
    }
}

// ===================== attention core =====================
// block = one (b,h); 4 waves. bid mapping keeps all 8 heads of a b on one XCD.
__global__ __launch_bounds__(256) void attn_kernel(
    const float* __restrict__ x,
    const float* __restrict__ bq, const float* __restrict__ bkv,
    const float* __restrict__ Wgate, const float* __restrict__ bgate,
    unsigned char* __restrict__ ws)
{
    // tile regions (bytes): phase1: xs [64 rows][512B] swizzled (32 KB)
    // post-QKV overlay: q[0,8K) -> later Ab; k[8K,16K); vT[16K,20K); ua[20K,24K); ub[24K,28K)
    __shared__ __align__(16) unsigned char tile[32768];
    __shared__ float As[64 * 68];
    __shared__ float dn[64];
    __shared__ float gw[4];

    const int bid = blockIdx.x;
    const int b = bid & 1023, h = bid >> 10;
    const int t = threadIdx.x;
    const int l = t & 63, w = t >> 6;
    const int lr = l & 15, qg = l >> 4;

    // ---- phase 1: stage x[b] -> swizzled bf16 LDS ----
    const float* xb = x + (size_t)b * 16384;
    #pragma unroll
    for (int i = 0; i < 8; i++) {
        int e = t + i * 256;
        int row = e >> 5, c = e & 31;
        const float4* p = (const float4*)(xb + row * 256 + c * 8);
        float4 f0 = p[0], f1 = p[1];
        uint4 u;
        u.x = pk2(f0.x, f0.y); u.y = pk2(f0.z, f0.w);
        u.z = pk2(f1.x, f1.y); u.w = pk2(f1.z, f1.w);
        *(uint4*)(tile + row * 512 + ((c >> 3) << 7) + (((c & 7) ^ (row & 7)) << 4)) = u;
    }
    __syncthreads();

    // ---- phase 2: QKV MFMA. wave w owns rows [w*16, w*16+16), cols q|k|v (2 tiles each) ----
    f32x4 aq[2], ak[2], av[2];
    #pragma unroll
    for (int ct = 0; ct < 2; ct++) {
        int o = h * 32 + ct * 16 + lr;
        float vq = bq[o], vk = bkv[o], vv = bkv[256 + o];
        f32x4 q0 = {vq, vq, vq, vq}; aq[ct] = q0;
        f32x4 k0 = {vk, vk, vk, vk}; ak[ct] = k0;
        f32x4 v0 = {vv, vv, vv, vv}; av[ct] = v0;
    }
    {
        const uint4* WQp = (const uint4*)(ws + WS_WQ);
        const uint4* WKp = (const uint4*)(ws + WS_WK);
        const uint4* WVp = (const uint4*)(ws + WS_WV);
        const int rowA = w * 16 + lr;
        #pragma unroll 2
        for (int ks = 0; ks < 8; ks++) {
            int c = ks * 4 + qg;
            bf16x8 af = *(const bf16x8*)(tile + rowA * 512 + ((c >> 3) << 7) + (((c & 7) ^ (lr & 7)) << 4));
            #pragma unroll
            for (int ct = 0; ct < 2; ct++) {
                int idx = (h * 32 + ct * 16 + lr) * 32 + ks * 4 + qg;
                aq[ct] = __builtin_amdgcn_mfma_f32_16x16x32_bf16(af, as_bf(WQp[idx]), aq[ct], 0, 0, 0);
                ak[ct] = __builtin_amdgcn_mfma_f32_16x16x32_bf16(af, as_bf(WKp[idx]), ak[ct], 0, 0, 0);
                av[ct] = __builtin_amdgcn_mfma_f32_16x16x32_bf16(af, as_bf(WVp[idx]), av[ct], 0, 0, 0);
            }
        }
    }
    __syncthreads();

    // ---- phase 3: row softmax on q and k, in C-register layout (cols = 2 tiles) ----
    #pragma unroll
    for (int r = 0; r < 4; r++) {
        {
            float m = fmaxf(aq[0][r], aq[1][r]);
            m = fmaxf(m, __shfl_xor(m, 1)); m = fmaxf(m, __shfl_xor(m, 2));
            m = fmaxf(m, __shfl_xor(m, 4)); m = fmaxf(m, __shfl_xor(m, 8));
            float e0 = __expf(aq[0][r] - m), e1 = __expf(aq[1][r] - m);
            float s = e0 + e1;
            s += __shfl_xor(s, 1); s += __shfl_xor(s, 2);
            s += __shfl_xor(s, 4); s += __shfl_xor(s, 8);
            float inv = 1.f / s;
            aq[0][r] = e0 * inv; aq[1][r] = e1 * inv;
        }
        {
            float m = fmaxf(ak[0][r], ak[1][r]);
            m = fmaxf(m, __shfl_xor(m, 1)); m = fmaxf(m, __shfl_xor(m, 2));
            m = fmaxf(m, __shfl_xor(m, 4)); m = fmaxf(m, __shfl_xor(m, 8));
            float e0 = __expf(ak[0][r] - m), e1 = __expf(ak[1][r] - m);
            float s = e0 + e1;
            s += __shfl_xor(s, 1); s += __shfl_xor(s, 2);
            s += __shfl_xor(s, 4); s += __shfl_xor(s, 8);
            float inv = 1.f / s;
            ak[0][r] = e0 * inv; ak[1][r] = e1 * inv;
        }
    }

    // ---- phase 4: spill q,k (row-major bf16, swizzled) and v^T; gate sigmoid ----
    #pragma unroll
    for (int ct = 0; ct < 2; ct++)
        #pragma unroll
        for (int r = 0; r < 4; r++) {
            int row = w * 16 + qg * 4 + r;
            int d = ct * 16 + lr;
            int byt = (((d >> 3) ^ (row & 7)) << 4) + (d & 7) * 2;
            *(short*)(tile + row * 128 + byt) = (short)f2bf(aq[ct][r]);
            *(short*)(tile + 8192 + row * 128 + byt) = (short)f2bf(ak[ct][r]);
            // v^T[d][row]
            *(short*)(tile + 16384 + d * 128 + (((row >> 3) ^ (d & 7)) << 4) + (row & 7) * 2) = (short)f2bf(av[ct][r]);
        }
    if (t < 4) {
        const float* xm = (const float*)(ws + WS_XMEAN) + b * 256 + h * 32;
        float s = bgate[t];
        #pragma unroll 8
        for (int dd = 0; dd < 32; dd++) s = fmaf(xm[dd], Wgate[dd * 4 + t], s);
        gw[t] = 1.f / (1.f + __expf(-s));
    }
    __syncthreads();
    if (t == 0) {
        float g0 = gw[0], g1 = gw[1], g2 = gw[2], g3 = gw[3];
        float a = 0.125f * g3, bb = 0.375f * g0, cc = 0.375f * g1, dd = 0.125f * g2;
        gw[0] = a + bb + cc + dd;
        gw[1] = 3.f * a + bb - cc - 3.f * dd;
        gw[2] = 3.f * a - bb - cc + 3.f * dd;
        gw[3] = a - bb + cc - dd;
    }

    // ---- phase 5: S = q k^T + relu(bias) -> As f32 ----
    {
        bf16x8 aqf = *(const bf16x8*)(tile + (w * 16 + lr) * 128 + ((qg ^ (lr & 7)) << 4));
        const float* bh = (const float*)(ws + WS_BIAS) + h * 4096;
        #pragma unroll
        for (int jt = 0; jt < 4; jt++) {
            bf16x8 bkf = *(const bf16x8*)(tile + 8192 + (jt * 16 + lr) * 128 + ((qg ^ (lr & 7)) << 4));
            f32x4 sc = {0.f, 0.f, 0.f, 0.f};
            sc = __builtin_amdgcn_mfma_f32_16x16x32_bf16(aqf, bkf, sc, 0, 0, 0);
            #pragma unroll
            for (int r = 0; r < 4; r++) {
                int i = w * 16 + qg * 4 + r, j = jt * 16 + lr;
                As[i * 68 + j] = sc[r] + bh[i * 64 + j];
            }
        }
    }
    __syncthreads();

    // ---- phase 6: symmetrize ----
    {
        int j = t & 63, i0 = (t >> 6) * 16;
        float sij[16], sji[16];
        #pragma unroll
        for (int rr = 0; rr < 16; rr++) { sij[rr] = As[(i0 + rr) * 68 + j]; sji[rr] = As[j * 68 + i0 + rr]; }
        __syncthreads();
        #pragma unroll
        for (int rr = 0; rr < 16; rr++) As[(i0 + rr) * 68 + j] = 0.5f * (sij[rr] + sji[rr]);
    }
    __syncthreads();

    // ---- phase 7: degrees ----
    if (t < 64) {
        float s = 0.f;
        #pragma unroll
        for (int k4 = 0; k4 < 16; k4++) {
            float4 v4 = *(const float4*)&As[t * 68 + k4 * 4];
            s += v4.x + v4.y + v4.z + v4.w;
        }
        dn[t] = (s > 0.f) ? rsqrtf(s) : s;
    }
    __syncthreads();

    // ---- phase 8: normalize + cvt -> Ab bf16 (overlays q region) ----
    {
        int i = t >> 2, j0 = (t & 3) * 16;
        float di = dn[i];
        float vals[16];
        #pragma unroll
        for (int e4 = 0; e4 < 4; e4++) {
            float4 v4 = *(const float4*)&As[i * 68 + j0 + e4 * 4];
            float4 d4 = *(const float4*)&dn[j0 + e4 * 4];
            vals[e4 * 4 + 0] = v4.x * di * d4.x;
            vals[e4 * 4 + 1] = v4.y * di * d4.y;
            vals[e4 * 4 + 2] = v4.z * di * d4.z;
            vals[e4 * 4 + 3] = v4.w * di * d4.w;
        }
        uint4 u0, u1;
        u0.x = pk2(vals[0], vals[1]);  u0.y = pk2(vals[2], vals[3]);
        u0.z = pk2(vals[4], vals[5]);  u0.w = pk2(vals[6], vals[7]);
        u1.x = pk2(vals[8], vals[9]);  u1.y = pk2(vals[10], vals[11]);
        u1.z = pk2(vals[12], vals[13]); u1.w = pk2(vals[14], vals[15]);
        int c0 = (t & 3) * 2;
        *(uint4*)(tile + i * 128 + (((c0) ^ (i & 7)) << 4)) = u0;
        *(uint4*)(tile + i * 128 + (((c0 + 1) ^ (i & 7)) << 4)) = u1;
    }
    __syncthreads();

    // ---- phase 9-11: y = w0 v + w1 Av + w2 A^2 v + w3 A^3 v ----
    const float w0 = gw[0], w1c = gw[1], w2c = gw[2], w3c = gw[3];
    f32x4 y[2];
    y[0] = av[0] * w0; y[1] = av[1] * w0;

#define AU_ROUND(SRC, DST, WC, WRITE) {                                                          \
    f32x4 u0 = {0.f,0.f,0.f,0.f}, u1 = {0.f,0.f,0.f,0.f};                                        \
    _Pragma("unroll")                                                                            \
    for (int ks2 = 0; ks2 < 2; ks2++) {                                                          \
        int c = ks2 * 4 + qg;                                                                    \
        bf16x8 af = *(const bf16x8*)(tile + (w * 16 + lr) * 128 + ((c ^ (lr & 7)) << 4));        \
        bf16x8 b0 = *(const bf16x8*)(tile + (SRC) + lr * 128 + ((c ^ (lr & 7)) << 4));           \
        bf16x8 b1 = *(const bf16x8*)(tile + (SRC) + (16 + lr) * 128 + ((c ^ (lr & 7)) << 4));    \
        u0 = __builtin_amdgcn_mfma_f32_16x16x32_bf16(af, b0, u0, 0, 0, 0);                       \
        u1 = __builtin_amdgcn_mfma_f32_16x16x32_bf16(af, b1, u1, 0, 0, 0);                       \
    }                                                                                            \
    y[0] += (WC) * u0; y[1] += (WC) * u1;                                                        \
    if (WRITE) {                                                                                 \
        _Pragma("unroll")                                                                        \
        for (int r = 0; r < 4; r++) {                                                            \
            int i = w * 16 + qg * 4 + r;                                                         \
            *(short*)(tile + (DST) + lr * 128 + (((i >> 3) ^ (lr & 7)) << 4) + (i & 7) * 2) = (short)f2bf(u0[r]); \
            *(short*)(tile + (DST) + (16 + lr) * 128 + (((i >> 3) ^ (lr & 7)) << 4) + (i & 7) * 2) = (short)f2bf(u1[r]); \
        }                                                                                        \
    }                                                                                            \
    __syncthreads();                                                                             \
}
    AU_ROUND(16384, 20480, w1c, 1)   // u1 = A v      -> ua
    AU_ROUND(20480, 24576, w2c, 1)   // u2 = A u1     -> ub
    AU_ROUND(24576, 0,     w3c, 0)   // u3 = A u2
#undef AU_ROUND

    // ---- write hidden bf16 ----
    unsigned short* hbf = (unsigned short*)ws;
    #pragma unroll
    for (int ct = 0; ct < 2; ct++)
        #pragma unroll
        for (int r = 0; r < 4; r++) {
            int row = w * 16 + qg * 4 + r;
            int col = h * 32 + ct * 16 + lr;
            hbf[((size_t)b * 64 + row) * 256 + col] = f2bf(y[ct][r]);
        }
}

// ===================== output projection =====================
// out[M=65536, 256] = hidden_bf @ Wproj + bproj ; block tile 128 x 64
__global__ __launch_bounds__(256) void proj_kernel(
    const unsigned char* __restrict__ ws,
    const float* __restrict__ bproj,
    float* __restrict__ out)
{
    __shared__ __align__(16) unsigned char atile[65536];
    const int rb = blockIdx.x, cb = blockIdx.y;
    const int t = threadIdx.x, l = t & 63, w = t >> 6;
    const int lr = l & 15, qg = l >> 4;

    const uint4* hsrc = (const uint4*)ws;
    #pragma unroll
    for (int i = 0; i < 16; i++) {
        int e = t + i * 256;
        int row = e >> 5, c = e & 31;
        uint4 u = hsrc[(size_t)(rb * 128 + row) * 32 + c];
        *(uint4*)(atile + row * 512 + ((c >> 3) << 7) + (((c & 7) ^ (row & 7)) << 4)) = u;
    }
    __syncthreads();

    const uint4* WP = (const uint4*)(ws + WS_WP);
    f32x4 acc[2][4];
    #pragma unroll
    for (int p = 0; p < 2; p++)
        #pragma unroll
        for (int ct = 0; ct < 4; ct++) { f32x4 z = {0.f,0.f,0.f,0.f}; acc[p][ct] = z; }

    #pragma unroll 2
    for (int ks = 0; ks < 8; ks++) {
        int c = ks * 4 + qg;
        int swz = ((c >> 3) << 7) + (((c & 7) ^ (lr & 7)) << 4);
        bf16x8 a0 = *(const bf16x8*)(atile + (w * 32 + lr) * 512 + swz);
        bf16x8 a1 = *(const bf16x8*)(atile + (w * 32 + 16 + lr) * 512 + swz);
        #pragma unroll
        for (int ct = 0; ct < 4; ct++) {
            bf16x8 bf = as_bf(WP[(cb * 64 + ct * 16 + lr) * 32 + ks * 4 + qg]);
            acc[0][ct] = __builtin_amdgcn_mfma_f32_16x16x32_bf16(a0, bf, acc[0][ct], 0, 0, 0);
            acc[1][ct] = __builtin_amdgcn_mfma_f32_16x16x32_bf16(a1, bf, acc[1][ct], 0, 0, 0);
        }
    }

    #pragma unroll
    for (int p = 0; p < 2; p++)
        #pragma unroll
        for (int ct = 0; ct < 4; ct++) {
            int colg = cb * 64 + ct * 16 + lr;
            float bz = bproj[colg];
            #pragma unroll
            for (int r = 0; r < 4; r++) {
                int rowg = rb * 128 + w * 32 + p * 16 + qg * 4 + r;
                out[(size_t)rowg * 256 + colg] = acc[p][ct][r] + bz;
            }
        }
}

extern "C" void kernel_launch(void* const* d_in, const int* in_sizes, int n_in,
                              void* d_out, int out_size, void* d_ws, size_t ws_size,
                              hipStream_t stream) {
    const float* x          = (const float*)d_in[0];
    const float* Wq         = (const float*)d_in[1];
    const float* bq         = (const float*)d_in[2];
    const float* Wkv        = (const float*)d_in[3];
    const float* bkv        = (const float*)d_in[4];
    const float* Wgate      = (const float*)d_in[5];
    const float* bgate      = (const float*)d_in[6];
    const float* Wproj      = (const float*)d_in[7];
    const float* bproj      = (const float*)d_in[8];
    const float* bias_table = (const float*)d_in[9];
    const int*   rel_index  = (const int*)d_in[10];
    float* out = (float*)d_out;
    unsigned char* wsb = (unsigned char*)d_ws;

    prep_kernel<<<dim3(2176), dim3(256), 0, stream>>>(x, Wq, Wkv, Wproj, bias_table, rel_index, wsb);
    attn_kernel<<<dim3(8192), dim3(256), 0, stream>>>(x, bq, bkv, Wgate, bgate, wsb);
    proj_kernel<<<dim3(512, 4), dim3(256), 0, stream>>>(wsb, bproj, out);
}

// Round 3
// 216.551 us; speedup vs baseline: 4.2677x; 1.4925x over previous
//
#include <hip/hip_runtime.h>

typedef __attribute__((ext_vector_type(8))) short bf16x8;
typedef __attribute__((ext_vector_type(4))) float f32x4;

// ---- workspace byte offsets ----
#define WS_HID    0u           // hidden bf16 [1024*64][256]  (33,554,432 B)
#define WS_WQ     33554432u    // Wq^T  bf16 [256 out][256 k]
#define WS_WK     33685504u    // Wk^T  bf16
#define WS_WV     33816576u    // Wv^T  bf16
#define WS_WP     33947648u    // Wproj^T bf16
#define WS_BIAS   34078720u    // relu(bias) f32 [8][64][64]
#define WS_XMEAN  34209792u    // x col-means f32 [1024][256]
#define WS_W      35258368u    // poly weights f32 [8192][4]

__device__ __forceinline__ unsigned short f2bf(float f) {
    unsigned int u = __float_as_uint(f);
    u += 0x7FFFu + ((u >> 16) & 1u);   // RNE
    return (unsigned short)(u >> 16);
}
__device__ __forceinline__ unsigned int pk2(float lo, float hi) {
    return (unsigned int)f2bf(lo) | ((unsigned int)f2bf(hi) << 16);
}
__device__ __forceinline__ bf16x8 as_bf(uint4 u) {
    union { uint4 a; bf16x8 b; } c; c.a = u; return c.b;
}
__device__ __forceinline__ float bf2f(unsigned short us) {
    return __uint_as_float(((unsigned int)us) << 16);
}

// ===================== prep =====================
__global__ __launch_bounds__(256) void prep_kernel(
    const float* __restrict__ x, const float* __restrict__ Wq,
    const float* __restrict__ Wkv, const float* __restrict__ Wproj,
    const float* __restrict__ bias_table, const int* __restrict__ rel_index,
    unsigned char* __restrict__ ws)
{
    const int bid = blockIdx.x, t = threadIdx.x;
    if (bid < 1024) {
        // column means of x[b] over N=64
        float s = 0.f;
        const float* xb = x + (size_t)bid * 16384 + t;
        #pragma unroll 8
        for (int n = 0; n < 64; n++) s += xb[n * 256];
        ((float*)(ws + WS_XMEAN))[bid * 256 + t] = s * (1.f / 64.f);
    } else if (bid < 2048) {
        // transpose-pack 4 weight matrices to bf16: dst[o][k] = src[k][o]
        int e = (bid - 1024) * 256 + t;
        int m = e >> 16, r = e & 65535, o = r >> 8, kk = r & 255;
        float v; unsigned short* dst;
        if (m == 0)      { v = Wq[kk * 256 + o];         dst = (unsigned short*)(ws + WS_WQ); }
        else if (m == 1) { v = Wkv[kk * 512 + o];        dst = (unsigned short*)(ws + WS_WK); }
        else if (m == 2) { v = Wkv[kk * 512 + 256 + o];  dst = (unsigned short*)(ws + WS_WV); }
        else             { v = Wproj[kk * 256 + o];      dst = (unsigned short*)(ws + WS_WP); }
        dst[o * 256 + kk] = f2bf(v);
    } else {
        // pre-relu positional bias: [h][i*64+j]
        int e = (bid - 2048) * 256 + t;
        int hh = e >> 12, ij = e & 4095;
        ((float*)(ws + WS_BIAS))[hh * 4096 + ij] = fmaxf(bias_table[rel_index[ij] * 8 + hh], 0.f);
    }
}

// ===================== gate -> polynomial weights =====================
__global__ __launch_bounds__(256) void gate_kernel(
    const float* __restrict__ Wgate, const float* __restrict__ bgate,
    unsigned char* __restrict__ ws)
{
    int bh = blockIdx.x * 256 + threadIdx.x;   // 8192 = b*8+h
    int b = bh >> 3, h = bh & 7;
    const float* xm = (const float*)(ws + WS_XMEAN) + b * 256 + h * 32;
    float g[4];
    #pragma unroll
    for (int j = 0; j < 4; j++) {
        float s = bgate[j];
        #pragma unroll 8
        for (int dd = 0; dd < 32; dd++) s = fmaf(xm[dd], Wgate[dd * 4 + j], s);
        g[j] = 1.f / (1.f + __expf(-s));
    }
    float a = 0.125f * g[3], bb = 0.375f * g[0], cc = 0.375f * g[1], dd = 0.125f * g[2];
    float4 o;
    o.x = a + bb + cc + dd;
    o.y = 3.f * a + bb - cc - 3.f * dd;
    o.z = 3.f * a - bb - cc + 3.f * dd;
    o.w = a - bb + cc - dd;
    ((float4*)(ws + WS_W))[bh] = o;
}

// ===================== attention core =====================
// block = one (b,h); 4 waves with QKV role split: w0=q, w1=k, w2/w3=v halves.
__global__ __launch_bounds__(256, 3) void attn_kernel(
    const float* __restrict__ x,
    const float* __restrict__ bq, const float* __restrict__ bkv,
    unsigned char* __restrict__ ws)
{
    // tile regions (bytes): phase1: xs [64 rows][512B] swizzled (32 KB)
    // post-QKV overlay: q[0,8K) -> later Ab; k[8K,16K); vT[16K,20K); ua[20K,24K); ub[24K,28K)
    __shared__ __align__(16) unsigned char tile[32768];
    __shared__ float As[64 * 65];
    __shared__ float dn[64];

    const int bid = blockIdx.x;
    const int b = bid & 1023, h = bid >> 10;   // heads of a b share an XCD
    const int t = threadIdx.x;
    const int l = t & 63, w = t >> 6;
    const int lr = l & 15, qg = l >> 4;

    const float4 wv4 = ((const float4*)(ws + WS_W))[b * 8 + h];

    // ---- hoist weight B-fragments into registers (issued before staging) ----
    const int role = w;                      // 0=q, 1=k, 2=v(d 0..15), 3=v(d 16..31)
    uint4 Bfr0[8], Bfr1[8];
    {
        const unsigned off = (role == 0) ? WS_WQ : (role == 1) ? WS_WK : WS_WV;
        const uint4* Wp = (const uint4*)(ws + off);
        const int ct0 = (role < 2) ? 0 : (role - 2);
        const int o0 = h * 32 + ct0 * 16 + lr;
        #pragma unroll
        for (int ks = 0; ks < 8; ks++) Bfr0[ks] = Wp[o0 * 32 + ks * 4 + qg];
        if (role < 2) {
            #pragma unroll
            for (int ks = 0; ks < 8; ks++) Bfr1[ks] = Wp[(o0 + 16) * 32 + ks * 4 + qg];
        }
    }

    // ---- phase 1: stage x[b] -> swizzled bf16 LDS ----
    const float* xb = x + (size_t)b * 16384;
    #pragma unroll
    for (int i = 0; i < 8; i++) {
        int e = t + i * 256;
        int row = e >> 5, c = e & 31;
        const float4* p = (const float4*)(xb + row * 256 + c * 8);
        float4 f0 = p[0], f1 = p[1];
        uint4 u;
        u.x = pk2(f0.x, f0.y); u.y = pk2(f0.z, f0.w);
        u.z = pk2(f1.x, f1.y); u.w = pk2(f1.z, f1.w);
        *(uint4*)(tile + row * 512 + ((c >> 3) << 7) + (((c & 7) ^ (row & 7)) << 4)) = u;
    }

    // bias-init accumulators
    f32x4 acc0[4], acc1[4];
    {
        const int ct0 = (role < 2) ? 0 : (role - 2);
        const int o0 = h * 32 + ct0 * 16 + lr;
        float b0 = (role == 0) ? bq[o0] : (role == 1) ? bkv[o0] : bkv[256 + o0];
        float b1 = (role == 0) ? bq[o0 + 16] : (role == 1) ? bkv[o0 + 16] : 0.f;
        #pragma unroll
        for (int mt = 0; mt < 4; mt++) {
            f32x4 z0 = {b0, b0, b0, b0}; acc0[mt] = z0;
            f32x4 z1 = {b1, b1, b1, b1}; acc1[mt] = z1;
        }
    }
    __syncthreads();

    // ---- phase 2: QKV MFMA, zero global loads in loop ----
    if (role < 2) {
        #pragma unroll
        for (int mt = 0; mt < 4; mt++) {
            const int rowA = mt * 16 + lr;
            #pragma unroll
            for (int ks = 0; ks < 8; ks++) {
                const int c = ks * 4 + qg;
                bf16x8 af = *(const bf16x8*)(tile + rowA * 512 + ((c >> 3) << 7) + (((c & 7) ^ (rowA & 7)) << 4));
                acc0[mt] = __builtin_amdgcn_mfma_f32_16x16x32_bf16(af, as_bf(Bfr0[ks]), acc0[mt], 0, 0, 0);
                acc1[mt] = __builtin_amdgcn_mfma_f32_16x16x32_bf16(af, as_bf(Bfr1[ks]), acc1[mt], 0, 0, 0);
            }
        }
    } else {
        #pragma unroll
        for (int mt = 0; mt < 4; mt++) {
            const int rowA = mt * 16 + lr;
            #pragma unroll
            for (int ks = 0; ks < 8; ks++) {
                const int c = ks * 4 + qg;
                bf16x8 af = *(const bf16x8*)(tile + rowA * 512 + ((c >> 3) << 7) + (((c & 7) ^ (rowA & 7)) << 4));
                acc0[mt] = __builtin_amdgcn_mfma_f32_16x16x32_bf16(af, as_bf(Bfr0[ks]), acc0[mt], 0, 0, 0);
            }
        }
    }
    __syncthreads();

    // ---- phase 3: row softmax for q (wave0) / k (wave1), in registers ----
    if (role < 2) {
        #pragma unroll
        for (int mt = 0; mt < 4; mt++)
            #pragma unroll
            for (int r = 0; r < 4; r++) {
                float v0 = acc0[mt][r], v1 = acc1[mt][r];
                float m = fmaxf(v0, v1);
                m = fmaxf(m, __shfl_xor(m, 1)); m = fmaxf(m, __shfl_xor(m, 2));
                m = fmaxf(m, __shfl_xor(m, 4)); m = fmaxf(m, __shfl_xor(m, 8));
                float e0 = __expf(v0 - m), e1 = __expf(v1 - m);
                float s = e0 + e1;
                s += __shfl_xor(s, 1); s += __shfl_xor(s, 2);
                s += __shfl_xor(s, 4); s += __shfl_xor(s, 8);
                float inv = 1.f / s;
                acc0[mt][r] = e0 * inv; acc1[mt][r] = e1 * inv;
            }
    }

    // ---- phase 4: spill q,k,vT to LDS (byte layouts identical to verified R2) ----
    if (role == 0) {
        #pragma unroll
        for (int mt = 0; mt < 4; mt++)
            #pragma unroll
            for (int r = 0; r < 4; r++) {
                int row = mt * 16 + qg * 4 + r;
                int d0 = lr, d1 = 16 + lr;
                *(short*)(tile + row * 128 + (((d0 >> 3) ^ (row & 7)) << 4) + (d0 & 7) * 2) = (short)f2bf(acc0[mt][r]);
                *(short*)(tile + row * 128 + (((d1 >> 3) ^ (row & 7)) << 4) + (d1 & 7) * 2) = (short)f2bf(acc1[mt][r]);
            }
    } else if (role == 1) {
        #pragma unroll
        for (int mt = 0; mt < 4; mt++)
            #pragma unroll
            for (int r = 0; r < 4; r++) {
                int row = mt * 16 + qg * 4 + r;
                int d0 = lr, d1 = 16 + lr;
                *(short*)(tile + 8192 + row * 128 + (((d0 >> 3) ^ (row & 7)) << 4) + (d0 & 7) * 2) = (short)f2bf(acc0[mt][r]);
                *(short*)(tile + 8192 + row * 128 + (((d1 >> 3) ^ (row & 7)) << 4) + (d1 & 7) * 2) = (short)f2bf(acc1[mt][r]);
            }
    } else {
        const int d = (role - 2) * 16 + lr;
        #pragma unroll
        for (int mt = 0; mt < 4; mt++)
            #pragma unroll
            for (int r = 0; r < 4; r++) {
                int row = mt * 16 + qg * 4 + r;
                *(short*)(tile + 16384 + d * 128 + (((row >> 3) ^ (d & 7)) << 4) + (row & 7) * 2) = (short)f2bf(acc0[mt][r]);
            }
    }
    __syncthreads();

    // ---- phase 5: S = q k^T + relu(bias) -> As f32 (stride 65) ----
    {
        bf16x8 aqf = *(const bf16x8*)(tile + (w * 16 + lr) * 128 + ((qg ^ (lr & 7)) << 4));
        const float* bh_ = (const float*)(ws + WS_BIAS) + h * 4096;
        #pragma unroll
        for (int jt = 0; jt < 4; jt++) {
            bf16x8 bkf = *(const bf16x8*)(tile + 8192 + (jt * 16 + lr) * 128 + ((qg ^ (lr & 7)) << 4));
            f32x4 sc = {0.f, 0.f, 0.f, 0.f};
            sc = __builtin_amdgcn_mfma_f32_16x16x32_bf16(aqf, bkf, sc, 0, 0, 0);
            #pragma unroll
            for (int r = 0; r < 4; r++) {
                int i = w * 16 + qg * 4 + r, j = jt * 16 + lr;
                As[i * 65 + j] = sc[r] + bh_[i * 64 + j];
            }
        }
    }
    __syncthreads();

    // ---- phase 6: symmetrize ----
    {
        int j = t & 63, i0 = (t >> 6) * 16;
        float sij[16], sji[16];
        #pragma unroll
        for (int rr = 0; rr < 16; rr++) { sij[rr] = As[(i0 + rr) * 65 + j]; sji[rr] = As[j * 65 + i0 + rr]; }
        __syncthreads();
        #pragma unroll
        for (int rr = 0; rr < 16; rr++) As[(i0 + rr) * 65 + j] = 0.5f * (sij[rr] + sji[rr]);
    }
    __syncthreads();

    // ---- phase 7: degrees ----
    if (t < 64) {
        float s = 0.f;
        #pragma unroll 8
        for (int j = 0; j < 64; j++) s += As[t * 65 + j];
        dn[t] = (s > 0.f) ? rsqrtf(s) : s;
    }
    __syncthreads();

    // ---- phase 8: normalize + cvt -> Ab bf16 (overlays q region) ----
    {
        int i = t >> 2, j0 = (t & 3) * 16;
        float di = dn[i];
        float vals[16];
        #pragma unroll
        for (int jj = 0; jj < 16; jj++) vals[jj] = As[i * 65 + j0 + jj] * di * dn[j0 + jj];
        uint4 u0, u1;
        u0.x = pk2(vals[0], vals[1]);   u0.y = pk2(vals[2], vals[3]);
        u0.z = pk2(vals[4], vals[5]);   u0.w = pk2(vals[6], vals[7]);
        u1.x = pk2(vals[8], vals[9]);   u1.y = pk2(vals[10], vals[11]);
        u1.z = pk2(vals[12], vals[13]); u1.w = pk2(vals[14], vals[15]);
        int c0 = (t & 3) * 2;
        *(uint4*)(tile + i * 128 + (((c0) ^ (i & 7)) << 4)) = u0;
        *(uint4*)(tile + i * 128 + (((c0 + 1) ^ (i & 7)) << 4)) = u1;
    }
    __syncthreads();

    // ---- phase 9-11: y = w0 v + w1 Av + w2 A^2 v + w3 A^3 v ----
    const float w0c = wv4.x, w1c = wv4.y, w2c = wv4.z, w3c = wv4.w;
    f32x4 y[2];
    #pragma unroll
    for (int ct = 0; ct < 2; ct++)
        #pragma unroll
        for (int r = 0; r < 4; r++) {
            int row = w * 16 + qg * 4 + r;
            int d = ct * 16 + lr;
            unsigned short us = *(unsigned short*)(tile + 16384 + d * 128 + (((row >> 3) ^ (d & 7)) << 4) + (row & 7) * 2);
            y[ct][r] = w0c * bf2f(us);
        }

#define AU_ROUND(SRC, DST, WC, WRITE) {                                                          \
    f32x4 u0 = {0.f,0.f,0.f,0.f}, u1 = {0.f,0.f,0.f,0.f};                                        \
    _Pragma("unroll")                                                                            \
    for (int ks2 = 0; ks2 < 2; ks2++) {                                                          \
        int c = ks2 * 4 + qg;                                                                    \
        bf16x8 af = *(const bf16x8*)(tile + (w * 16 + lr) * 128 + ((c ^ (lr & 7)) << 4));        \
        bf16x8 b0 = *(const bf16x8*)(tile + (SRC) + lr * 128 + ((c ^ (lr & 7)) << 4));           \
        bf16x8 b1 = *(const bf16x8*)(tile + (SRC) + (16 + lr) * 128 + ((c ^ (lr & 7)) << 4));    \
        u0 = __builtin_amdgcn_mfma_f32_16x16x32_bf16(af, b0, u0, 0, 0, 0);                       \
        u1 = __builtin_amdgcn_mfma_f32_16x16x32_bf16(af, b1, u1, 0, 0, 0);                       \
    }                                                                                            \
    y[0] += (WC) * u0; y[1] += (WC) * u1;                                                        \
    if (WRITE) {                                                                                 \
        _Pragma("unroll")                                                                        \
        for (int r = 0; r < 4; r++) {                                                            \
            int i = w * 16 + qg * 4 + r;                                                         \
            *(short*)(tile + (DST) + lr * 128 + (((i >> 3) ^ (lr & 7)) << 4) + (i & 7) * 2) = (short)f2bf(u0[r]); \
            *(short*)(tile + (DST) + (16 + lr) * 128 + (((i >> 3) ^ (lr & 7)) << 4) + (i & 7) * 2) = (short)f2bf(u1[r]); \
        }                                                                                        \
    }                                                                                            \
    __syncthreads();                                                                             \
}
    AU_ROUND(16384, 20480, w1c, 1)   // u1 = A v      -> ua
    AU_ROUND(20480, 24576, w2c, 1)   // u2 = A u1     -> ub
    AU_ROUND(24576, 0,     w3c, 0)   // u3 = A u2
#undef AU_ROUND

    // ---- write hidden bf16 ----
    unsigned short* hbf = (unsigned short*)ws;
    #pragma unroll
    for (int ct = 0; ct < 2; ct++)
        #pragma unroll
        for (int r = 0; r < 4; r++) {
            int row = w * 16 + qg * 4 + r;
            int col = h * 32 + ct * 16 + lr;
            hbf[((size_t)b * 64 + row) * 256 + col] = f2bf(y[ct][r]);
        }
}

// ===================== output projection =====================
// out[M=65536, 256] = hidden_bf @ Wproj + bproj ; block tile 128 x 64
__global__ __launch_bounds__(256) void proj_kernel(
    const unsigned char* __restrict__ ws,
    const float* __restrict__ bproj,
    float* __restrict__ out)
{
    __shared__ __align__(16) unsigned char atile[65536];
    const int rb = blockIdx.x, cb = blockIdx.y;
    const int t = threadIdx.x, l = t & 63, w = t >> 6;
    const int lr = l & 15, qg = l >> 4;

    const uint4* hsrc = (const uint4*)ws;
    #pragma unroll
    for (int i = 0; i < 16; i++) {
        int e = t + i * 256;
        int row = e >> 5, c = e & 31;
        uint4 u = hsrc[(size_t)(rb * 128 + row) * 32 + c];
        *(uint4*)(atile + row * 512 + ((c >> 3) << 7) + (((c & 7) ^ (row & 7)) << 4)) = u;
    }
    __syncthreads();

    const uint4* WP = (const uint4*)(ws + WS_WP);
    f32x4 acc[2][4];
    #pragma unroll
    for (int p = 0; p < 2; p++)
        #pragma unroll
        for (int ct = 0; ct < 4; ct++) { f32x4 z = {0.f,0.f,0.f,0.f}; acc[p][ct] = z; }

    #pragma unroll 2
    for (int ks = 0; ks < 8; ks++) {
        int c = ks * 4 + qg;
        int swz = ((c >> 3) << 7) + (((c & 7) ^ (lr & 7)) << 4);
        bf16x8 a0 = *(const bf16x8*)(atile + (w * 32 + lr) * 512 + swz);
        bf16x8 a1 = *(const bf16x8*)(atile + (w * 32 + 16 + lr) * 512 + swz);
        #pragma unroll
        for (int ct = 0; ct < 4; ct++) {
            bf16x8 bf = as_bf(WP[(cb * 64 + ct * 16 + lr) * 32 + ks * 4 + qg]);
            acc[0][ct] = __builtin_amdgcn_mfma_f32_16x16x32_bf16(a0, bf, acc[0][ct], 0, 0, 0);
            acc[1][ct] = __builtin_amdgcn_mfma_f32_16x16x32_bf16(a1, bf, acc[1][ct], 0, 0, 0);
        }
    }

    #pragma unroll
    for (int p = 0; p < 2; p++)
        #pragma unroll
        for (int ct = 0; ct < 4; ct++) {
            int colg = cb * 64 + ct * 16 + lr;
            float bz = bproj[colg];
            #pragma unroll
            for (int r = 0; r < 4; r++) {
                int rowg = rb * 128 + w * 32 + p * 16 + qg * 4 + r;
                out[(size_t)rowg * 256 + colg] = acc[p][ct][r] + bz;
            }
        }
}

extern "C" void kernel_launch(void* const* d_in, const int* in_sizes, int n_in,
                              void* d_out, int out_size, void* d_ws, size_t ws_size,
                              hipStream_t stream) {
    const float* x          = (const float*)d_in[0];
    const float* Wq         = (const float*)d_in[1];
    const float* bq         = (const float*)d_in[2];
    const float* Wkv        = (const float*)d_in[3];
    const float* bkv        = (const float*)d_in[4];
    const float* Wgate      = (const float*)d_in[5];
    const float* bgate      = (const float*)d_in[6];
    const float* Wproj      = (const float*)d_in[7];
    const float* bproj      = (const float*)d_in[8];
    const float* bias_table = (const float*)d_in[9];
    const int*   rel_index  = (const int*)d_in[10];
    float* out = (float*)d_out;
    unsigned char* wsb = (unsigned char*)d_ws;

    prep_kernel<<<dim3(2176), dim3(256), 0, stream>>>(x, Wq, Wkv, Wproj, bias_table, rel_index, wsb);
    gate_kernel<<<dim3(32), dim3(256), 0, stream>>>(Wgate, bgate, wsb);
    attn_kernel<<<dim3(8192), dim3(256), 0, stream>>>(x, bq, bkv, wsb);
    proj_kernel<<<dim3(512, 4), dim3(256), 0, stream>>>(wsb, bproj, out);
}

// Round 4
// 178.146 us; speedup vs baseline: 5.1877x; 1.2156x over previous
//
#include <hip/hip_runtime.h>

typedef __attribute__((ext_vector_type(8))) short bf16x8;
typedef __attribute__((ext_vector_type(4))) float f32x4;

#define AST 68   // As row stride (floats); 68%32=4 -> max 2-way bank conflict, float4-aligned

__device__ __forceinline__ unsigned short f2bf(float f) {
    unsigned int u = __float_as_uint(f);
    u += 0x7FFFu + ((u >> 16) & 1u);   // RNE
    return (unsigned short)(u >> 16);
}
__device__ __forceinline__ unsigned int pk2(float lo, float hi) {
    return (unsigned int)f2bf(lo) | ((unsigned int)f2bf(hi) << 16);
}
__device__ __forceinline__ bf16x8 as_bf(uint4 u) {
    union { uint4 a; bf16x8 b; } c; c.a = u; return c.b;
}
__device__ __forceinline__ float bf2f(unsigned short us) {
    return __uint_as_float(((unsigned int)us) << 16);
}
// async global->LDS, 16B/lane; lds dest = wave-uniform base + lane*16 (HW rule)
__device__ __forceinline__ void gload_lds16(const void* g, void* l) {
    __builtin_amdgcn_global_load_lds(
        (const __attribute__((address_space(1))) void*)g,
        (__attribute__((address_space(3))) void*)l, 16, 0, 0);
}

// ===================== prep: x->bf16 + means + gate/poly, weight pack, bias =====================
__global__ __launch_bounds__(256) void prep_kernel(
    const float* __restrict__ x,
    const float* __restrict__ Wq, const float* __restrict__ Wkv, const float* __restrict__ Wproj,
    const float* __restrict__ Wgate, const float* __restrict__ bgate,
    const float* __restrict__ bias_table, const int* __restrict__ rel_index,
    unsigned short* __restrict__ xbf, int use_xbf,
    unsigned short* __restrict__ wq, unsigned short* __restrict__ wk,
    unsigned short* __restrict__ wv, unsigned short* __restrict__ wp,
    float* __restrict__ biasws, float* __restrict__ wpoly)
{
    const int bid = blockIdx.x, t = threadIdx.x;
    if (bid < 1024) {
        __shared__ float mean_s[256];
        __shared__ float gsig[32];
        const float* xb = x + (size_t)bid * 16384;
        float s = 0.f;
        if (use_xbf) {
            unsigned short* xo = xbf + (size_t)bid * 16384;
            #pragma unroll 4
            for (int n = 0; n < 64; n++) { float v = xb[n * 256 + t]; s += v; xo[n * 256 + t] = f2bf(v); }
        } else {
            #pragma unroll 8
            for (int n = 0; n < 64; n++) s += xb[n * 256 + t];
        }
        mean_s[t] = s * (1.f / 64.f);
        __syncthreads();
        if (t < 32) {
            int h = t >> 2, j = t & 3;
            float g = bgate[j];
            #pragma unroll 8
            for (int dd = 0; dd < 32; dd++) g = fmaf(mean_s[h * 32 + dd], Wgate[dd * 4 + j], g);
            gsig[t] = 1.f / (1.f + __expf(-g));
        }
        __syncthreads();
        if (t < 8) {
            float g0 = gsig[t * 4], g1 = gsig[t * 4 + 1], g2 = gsig[t * 4 + 2], g3 = gsig[t * 4 + 3];
            float a = 0.125f * g3, bb = 0.375f * g0, cc = 0.375f * g1, dd = 0.125f * g2;
            float4 o;
            o.x = a + bb + cc + dd;
            o.y = 3.f * a + bb - cc - 3.f * dd;
            o.z = 3.f * a - bb - cc + 3.f * dd;
            o.w = a - bb + cc - dd;
            ((float4*)wpoly)[bid * 8 + t] = o;
        }
    } else if (bid < 2048) {
        // transpose-pack 4 weight matrices to bf16: dst[o][k] = src[k][o]
        int e = (bid - 1024) * 256 + t;
        int m = e >> 16, r = e & 65535, o = r >> 8, kk = r & 255;
        float v; unsigned short* dst;
        if (m == 0)      { v = Wq[kk * 256 + o];        dst = wq; }
        else if (m == 1) { v = Wkv[kk * 512 + o];       dst = wk; }
        else if (m == 2) { v = Wkv[kk * 512 + 256 + o]; dst = wv; }
        else             { v = Wproj[kk * 256 + o];     dst = wp; }
        dst[o * 256 + kk] = f2bf(v);
    } else {
        // pre-relu positional bias: [h][i*64+j]
        int e = (bid - 2048) * 256 + t;
        int hh = e >> 12, ij = e & 4095;
        biasws[hh * 4096 + ij] = fmaxf(bias_table[rel_index[ij] * 8 + hh], 0.f);
    }
}

// ===================== attention core =====================
// block = one (b,h); 4 waves, QKV role split: w0=q, w1=k, w2/w3=v halves.
// XCD-chunked swizzle: xcd=bid&7 owns b in [xcd*128, xcd*128+128), heads adjacent.
template <bool XBF>
__global__ __launch_bounds__(256, 3) void attn_kernel(
    const float* __restrict__ x, const unsigned short* __restrict__ xbf,
    const float* __restrict__ bq, const float* __restrict__ bkv,
    const unsigned short* __restrict__ wq, const unsigned short* __restrict__ wk,
    const unsigned short* __restrict__ wv,
    const float* __restrict__ biasws, const float* __restrict__ wpoly)
{
    // tile (bytes): phase1 xs [64 rows][512B] swizzled (32 KB)
    // post-QKV overlay: q[0,8K) -> later Ab; k[8K,16K); vT[16K,20K); ua[20K,24K); ub[24K,28K)
    __shared__ __align__(16) unsigned char tile[32768];
    __shared__ float As[64 * AST];
    __shared__ float dn[64];

    const int bid = blockIdx.x;
    const int xcd = bid & 7, idx = bid >> 3;
    const int b = xcd * 128 + (idx >> 3), h = idx & 7;
    const int t = threadIdx.x;
    const int l = t & 63, w = t >> 6;
    const int lr = l & 15, qg = l >> 4;

    const float4 wv4 = ((const float4*)wpoly)[b * 8 + h];

    // ---- hoist weight B-fragments (issued before staging) ----
    const int role = w;                      // 0=q, 1=k, 2=v(d 0..15), 3=v(d 16..31)
    uint4 Bfr0[8], Bfr1[8];
    {
        const unsigned short* wsel = (role == 0) ? wq : (role == 1) ? wk : wv;
        const uint4* Wp = (const uint4*)wsel;
        const int ct0 = (role < 2) ? 0 : (role - 2);
        const int o0 = h * 32 + ct0 * 16 + lr;
        #pragma unroll
        for (int ks = 0; ks < 8; ks++) Bfr0[ks] = Wp[o0 * 32 + ks * 4 + qg];
        if (role < 2) {
            #pragma unroll
            for (int ks = 0; ks < 8; ks++) Bfr1[ks] = Wp[(o0 + 16) * 32 + ks * 4 + qg];
        }
    }

    // ---- phase 1: stage x[b] -> swizzled bf16 LDS ----
    if (XBF) {
        const unsigned short* xb = xbf + (size_t)b * 16384;
        const int row_in_pair = l >> 5, u = l & 31;
        #pragma unroll
        for (int i = 0; i < 8; i++) {
            int row = i * 8 + w * 2 + row_in_pair;
            int csrc = (u & 24) | ((u & 7) ^ (row & 7));   // inverse of reader swizzle (involution)
            gload_lds16(xb + row * 256 + csrc * 8, tile + (i * 8 + w * 2) * 512);
        }
    } else {
        const float* xb = x + (size_t)b * 16384;
        #pragma unroll
        for (int i = 0; i < 8; i++) {
            int e = t + i * 256;
            int row = e >> 5, c = e & 31;
            const float4* p = (const float4*)(xb + row * 256 + c * 8);
            float4 f0 = p[0], f1 = p[1];
            uint4 u;
            u.x = pk2(f0.x, f0.y); u.y = pk2(f0.z, f0.w);
            u.z = pk2(f1.x, f1.y); u.w = pk2(f1.z, f1.w);
            *(uint4*)(tile + row * 512 + ((c >> 3) << 7) + (((c & 7) ^ (row & 7)) << 4)) = u;
        }
    }

    // bias-init accumulators
    f32x4 acc0[4], acc1[4];
    {
        const int ct0 = (role < 2) ? 0 : (role - 2);
        const int o0 = h * 32 + ct0 * 16 + lr;
        float b0 = (role == 0) ? bq[o0] : (role == 1) ? bkv[o0] : bkv[256 + o0];
        float b1 = (role == 0) ? bq[o0 + 16] : (role == 1) ? bkv[o0 + 16] : 0.f;
        #pragma unroll
        for (int mt = 0; mt < 4; mt++) {
            f32x4 z0 = {b0, b0, b0, b0}; acc0[mt] = z0;
            f32x4 z1 = {b1, b1, b1, b1}; acc1[mt] = z1;
        }
    }
    __syncthreads();

    // ---- phase 2: QKV MFMA, zero global loads in loop ----
    if (role < 2) {
        #pragma unroll
        for (int mt = 0; mt < 4; mt++) {
            const int rowA = mt * 16 + lr;
            #pragma unroll
            for (int ks = 0; ks < 8; ks++) {
                const int c = ks * 4 + qg;
                bf16x8 af = *(const bf16x8*)(tile + rowA * 512 + ((c >> 3) << 7) + (((c & 7) ^ (rowA & 7)) << 4));
                acc0[mt] = __builtin_amdgcn_mfma_f32_16x16x32_bf16(af, as_bf(Bfr0[ks]), acc0[mt], 0, 0, 0);
                acc1[mt] = __builtin_amdgcn_mfma_f32_16x16x32_bf16(af, as_bf(Bfr1[ks]), acc1[mt], 0, 0, 0);
            }
        }
    } else {
        #pragma unroll
        for (int mt = 0; mt < 4; mt++) {
            const int rowA = mt * 16 + lr;
            #pragma unroll
            for (int ks = 0; ks < 8; ks++) {
                const int c = ks * 4 + qg;
                bf16x8 af = *(const bf16x8*)(tile + rowA * 512 + ((c >> 3) << 7) + (((c & 7) ^ (rowA & 7)) << 4));
                acc0[mt] = __builtin_amdgcn_mfma_f32_16x16x32_bf16(af, as_bf(Bfr0[ks]), acc0[mt], 0, 0, 0);
            }
        }
    }
    __syncthreads();

    // ---- phase 3: row softmax for q (wave0) / k (wave1), in registers ----
    if (role < 2) {
        #pragma unroll
        for (int mt = 0; mt < 4; mt++)
            #pragma unroll
            for (int r = 0; r < 4; r++) {
                float v0 = acc0[mt][r], v1 = acc1[mt][r];
                float m = fmaxf(v0, v1);
                m = fmaxf(m, __shfl_xor(m, 1)); m = fmaxf(m, __shfl_xor(m, 2));
                m = fmaxf(m, __shfl_xor(m, 4)); m = fmaxf(m, __shfl_xor(m, 8));
                float e0 = __expf(v0 - m), e1 = __expf(v1 - m);
                float s = e0 + e1;
                s += __shfl_xor(s, 1); s += __shfl_xor(s, 2);
                s += __shfl_xor(s, 4); s += __shfl_xor(s, 8);
                float inv = 1.f / s;
                acc0[mt][r] = e0 * inv; acc1[mt][r] = e1 * inv;
            }
    }

    // ---- phase 4: spill q,k,vT to LDS ----
    if (role == 0) {
        #pragma unroll
        for (int mt = 0; mt < 4; mt++)
            #pragma unroll
            for (int r = 0; r < 4; r++) {
                int row = mt * 16 + qg * 4 + r;
                int d0 = lr, d1 = 16 + lr;
                *(short*)(tile + row * 128 + (((d0 >> 3) ^ (row & 7)) << 4) + (d0 & 7) * 2) = (short)f2bf(acc0[mt][r]);
                *(short*)(tile + row * 128 + (((d1 >> 3) ^ (row & 7)) << 4) + (d1 & 7) * 2) = (short)f2bf(acc1[mt][r]);
            }
    } else if (role == 1) {
        #pragma unroll
        for (int mt = 0; mt < 4; mt++)
            #pragma unroll
            for (int r = 0; r < 4; r++) {
                int row = mt * 16 + qg * 4 + r;
                int d0 = lr, d1 = 16 + lr;
                *(short*)(tile + 8192 + row * 128 + (((d0 >> 3) ^ (row & 7)) << 4) + (d0 & 7) * 2) = (short)f2bf(acc0[mt][r]);
                *(short*)(tile + 8192 + row * 128 + (((d1 >> 3) ^ (row & 7)) << 4) + (d1 & 7) * 2) = (short)f2bf(acc1[mt][r]);
            }
    } else {
        const int d = (role - 2) * 16 + lr;
        #pragma unroll
        for (int mt = 0; mt < 4; mt++)
            #pragma unroll
            for (int r = 0; r < 4; r++) {
                int row = mt * 16 + qg * 4 + r;
                *(short*)(tile + 16384 + d * 128 + (((row >> 3) ^ (d & 7)) << 4) + (row & 7) * 2) = (short)f2bf(acc0[mt][r]);
            }
    }
    __syncthreads();

    // ---- phase 5: S = q k^T + relu(bias) -> As f32 ----
    {
        bf16x8 aqf = *(const bf16x8*)(tile + (w * 16 + lr) * 128 + ((qg ^ (lr & 7)) << 4));
        const float* bh_ = biasws + h * 4096;
        #pragma unroll
        for (int jt = 0; jt < 4; jt++) {
            bf16x8 bkf = *(const bf16x8*)(tile + 8192 + (jt * 16 + lr) * 128 + ((qg ^ (lr & 7)) << 4));
            f32x4 sc = {0.f, 0.f, 0.f, 0.f};
            sc = __builtin_amdgcn_mfma_f32_16x16x32_bf16(aqf, bkf, sc, 0, 0, 0);
            #pragma unroll
            for (int r = 0; r < 4; r++) {
                int i = w * 16 + qg * 4 + r, j = jt * 16 + lr;
                As[i * AST + j] = sc[r] + bh_[i * 64 + j];
            }
        }
    }
    __syncthreads();

    // ---- phase 6: symmetrize ----
    {
        int j = t & 63, i0 = (t >> 6) * 16;
        float sij[16], sji[16];
        #pragma unroll
        for (int rr = 0; rr < 16; rr++) { sij[rr] = As[(i0 + rr) * AST + j]; sji[rr] = As[j * AST + i0 + rr]; }
        __syncthreads();
        #pragma unroll
        for (int rr = 0; rr < 16; rr++) As[(i0 + rr) * AST + j] = 0.5f * (sij[rr] + sji[rr]);
    }
    __syncthreads();

    // ---- phase 7: degrees (float4, AST%4==0) ----
    if (t < 64) {
        float s = 0.f;
        #pragma unroll
        for (int k4 = 0; k4 < 16; k4++) {
            float4 v4 = *(const float4*)&As[t * AST + k4 * 4];
            s += v4.x + v4.y + v4.z + v4.w;
        }
        dn[t] = (s > 0.f) ? rsqrtf(s) : s;
    }
    __syncthreads();

    // ---- phase 8: normalize + cvt -> Ab bf16 (overlays q region) ----
    {
        int i = t >> 2, j0 = (t & 3) * 16;
        float di = dn[i];
        float vals[16];
        #pragma unroll
        for (int e4 = 0; e4 < 4; e4++) {
            float4 v4 = *(const float4*)&As[i * AST + j0 + e4 * 4];
            float4 d4 = *(const float4*)&dn[j0 + e4 * 4];
            vals[e4 * 4 + 0] = v4.x * di * d4.x;
            vals[e4 * 4 + 1] = v4.y * di * d4.y;
            vals[e4 * 4 + 2] = v4.z * di * d4.z;
            vals[e4 * 4 + 3] = v4.w * di * d4.w;
        }
        uint4 u0, u1;
        u0.x = pk2(vals[0], vals[1]);   u0.y = pk2(vals[2], vals[3]);
        u0.z = pk2(vals[4], vals[5]);   u0.w = pk2(vals[6], vals[7]);
        u1.x = pk2(vals[8], vals[9]);   u1.y = pk2(vals[10], vals[11]);
        u1.z = pk2(vals[12], vals[13]); u1.w = pk2(vals[14], vals[15]);
        int c0 = (t & 3) * 2;
        *(uint4*)(tile + i * 128 + (((c0) ^ (i & 7)) << 4)) = u0;
        *(uint4*)(tile + i * 128 + (((c0 + 1) ^ (i & 7)) << 4)) = u1;
    }
    __syncthreads();

    // ---- phase 9-11: y = w0 v + w1 Av + w2 A^2 v + w3 A^3 v ----
    const float w0c = wv4.x, w1c = wv4.y, w2c = wv4.z, w3c = wv4.w;
    f32x4 y[2];
    #pragma unroll
    for (int ct = 0; ct < 2; ct++)
        #pragma unroll
        for (int r = 0; r < 4; r++) {
            int row = w * 16 + qg * 4 + r;
            int d = ct * 16 + lr;
            unsigned short us = *(unsigned short*)(tile + 16384 + d * 128 + (((row >> 3) ^ (d & 7)) << 4) + (row & 7) * 2);
            y[ct][r] = w0c * bf2f(us);
        }

#define AU_ROUND(SRC, DST, WC, WRITE) {                                                          \
    f32x4 u0 = {0.f,0.f,0.f,0.f}, u1 = {0.f,0.f,0.f,0.f};                                        \
    _Pragma("unroll")                                                                            \
    for (int ks2 = 0; ks2 < 2; ks2++) {                                                          \
        int c = ks2 * 4 + qg;                                                                    \
        bf16x8 af = *(const bf16x8*)(tile + (w * 16 + lr) * 128 + ((c ^ (lr & 7)) << 4));        \
        bf16x8 b0 = *(const bf16x8*)(tile + (SRC) + lr * 128 + ((c ^ (lr & 7)) << 4));           \
        bf16x8 b1 = *(const bf16x8*)(tile + (SRC) + (16 + lr) * 128 + ((c ^ (lr & 7)) << 4));    \
        u0 = __builtin_amdgcn_mfma_f32_16x16x32_bf16(af, b0, u0, 0, 0, 0);                       \
        u1 = __builtin_amdgcn_mfma_f32_16x16x32_bf16(af, b1, u1, 0, 0, 0);                       \
    }                                                                                            \
    y[0] += (WC) * u0; y[1] += (WC) * u1;                                                        \
    if (WRITE) {                                                                                 \
        _Pragma("unroll")                                                                        \
        for (int r = 0; r < 4; r++) {                                                            \
            int i = w * 16 + qg * 4 + r;                                                         \
            *(short*)(tile + (DST) + lr * 128 + (((i >> 3) ^ (lr & 7)) << 4) + (i & 7) * 2) = (short)f2bf(u0[r]); \
            *(short*)(tile + (DST) + (16 + lr) * 128 + (((i >> 3) ^ (lr & 7)) << 4) + (i & 7) * 2) = (short)f2bf(u1[r]); \
        }                                                                                        \
    }                                                                                            \
    __syncthreads();                                                                             \
}
    AU_ROUND(16384, 20480, w1c, 1)   // u1 = A v      -> ua
    AU_ROUND(20480, 24576, w2c, 1)   // u2 = A u1     -> ub
    AU_ROUND(24576, 0,     w3c, 0)   // u3 = A u2
#undef AU_ROUND

    // ---- write hidden bf16 ----
    unsigned short* hbf = (unsigned short*)0; // placeholder (set below)
    (void)hbf;
    {
        unsigned short* hid = (unsigned short*)(const_cast<unsigned short*>(xbf)); // unused in XBF=0
        (void)hid;
    }
    // hidden pointer passed via wpoly trick is ugly; use dedicated param instead:
    // (see hid param below)
}

// NOTE: hidden write needs its own param — re-declare attn with hid pointer.
// (The above template is replaced by attn2 below; attn_kernel kept minimal to avoid confusion.)

template <bool XBF>
__global__ __launch_bounds__(256, 3) void attn2_kernel(
    const float* __restrict__ x, const unsigned short* __restrict__ xbf,
    const float* __restrict__ bq, const float* __restrict__ bkv,
    const unsigned short* __restrict__ wq, const unsigned short* __restrict__ wk,
    const unsigned short* __restrict__ wv,
    const float* __restrict__ biasws, const float* __restrict__ wpoly,
    unsigned short* __restrict__ hid)
{
    __shared__ __align__(16) unsigned char tile[32768];
    __shared__ float As[64 * AST];
    __shared__ float dn[64];

    const int bid = blockIdx.x;
    const int xcd = bid & 7, idx = bid >> 3;
    const int b = xcd * 128 + (idx >> 3), h = idx & 7;
    const int t = threadIdx.x;
    const int l = t & 63, w = t >> 6;
    const int lr = l & 15, qg = l >> 4;

    const float4 wv4 = ((const float4*)wpoly)[b * 8 + h];

    const int role = w;
    uint4 Bfr0[8], Bfr1[8];
    {
        const unsigned short* wsel = (role == 0) ? wq : (role == 1) ? wk : wv;
        const uint4* Wp = (const uint4*)wsel;
        const int ct0 = (role < 2) ? 0 : (role - 2);
        const int o0 = h * 32 + ct0 * 16 + lr;
        #pragma unroll
        for (int ks = 0; ks < 8; ks++) Bfr0[ks] = Wp[o0 * 32 + ks * 4 + qg];
        if (role < 2) {
            #pragma unroll
            for (int ks = 0; ks < 8; ks++) Bfr1[ks] = Wp[(o0 + 16) * 32 + ks * 4 + qg];
        }
    }

    if (XBF) {
        const unsigned short* xb = xbf + (size_t)b * 16384;
        const int rp = l >> 5, u = l & 31;
        #pragma unroll
        for (int i = 0; i < 8; i++) {
            int row = i * 8 + w * 2 + rp;
            int csrc = (u & 24) | ((u & 7) ^ (row & 7));
            gload_lds16(xb + row * 256 + csrc * 8, tile + (i * 8 + w * 2) * 512);
        }
    } else {
        const float* xb = x + (size_t)b * 16384;
        #pragma unroll
        for (int i = 0; i < 8; i++) {
            int e = t + i * 256;
            int row = e >> 5, c = e & 31;
            const float4* p = (const float4*)(xb + row * 256 + c * 8);
            float4 f0 = p[0], f1 = p[1];
            uint4 u;
            u.x = pk2(f0.x, f0.y); u.y = pk2(f0.z, f0.w);
            u.z = pk2(f1.x, f1.y); u.w = pk2(f1.z, f1.w);
            *(uint4*)(tile + row * 512 + ((c >> 3) << 7) + (((c & 7) ^ (row & 7)) << 4)) = u;
        }
    }

    f32x4 acc0[4], acc1[4];
    {
        const int ct0 = (role < 2) ? 0 : (role - 2);
        const int o0 = h * 32 + ct0 * 16 + lr;
        float b0 = (role == 0) ? bq[o0] : (role == 1) ? bkv[o0] : bkv[256 + o0];
        float b1 = (role == 0) ? bq[o0 + 16] : (role == 1) ? bkv[o0 + 16] : 0.f;
        #pragma unroll
        for (int mt = 0; mt < 4; mt++) {
            f32x4 z0 = {b0, b0, b0, b0}; acc0[mt] = z0;
            f32x4 z1 = {b1, b1, b1, b1}; acc1[mt] = z1;
        }
    }
    __syncthreads();

    if (role < 2) {
        #pragma unroll
        for (int mt = 0; mt < 4; mt++) {
            const int rowA = mt * 16 + lr;
            #pragma unroll
            for (int ks = 0; ks < 8; ks++) {
                const int c = ks * 4 + qg;
                bf16x8 af = *(const bf16x8*)(tile + rowA * 512 + ((c >> 3) << 7) + (((c & 7) ^ (rowA & 7)) << 4));
                acc0[mt] = __builtin_amdgcn_mfma_f32_16x16x32_bf16(af, as_bf(Bfr0[ks]), acc0[mt], 0, 0, 0);
                acc1[mt] = __builtin_amdgcn_mfma_f32_16x16x32_bf16(af, as_bf(Bfr1[ks]), acc1[mt], 0, 0, 0);
            }
        }
    } else {
        #pragma unroll
        for (int mt = 0; mt < 4; mt++) {
            const int rowA = mt * 16 + lr;
            #pragma unroll
            for (int ks = 0; ks < 8; ks++) {
                const int c = ks * 4 + qg;
                bf16x8 af = *(const bf16x8*)(tile + rowA * 512 + ((c >> 3) << 7) + (((c & 7) ^ (rowA & 7)) << 4));
                acc0[mt] = __builtin_amdgcn_mfma_f32_16x16x32_bf16(af, as_bf(Bfr0[ks]), acc0[mt], 0, 0, 0);
            }
        }
    }
    __syncthreads();

    if (role < 2) {
        #pragma unroll
        for (int mt = 0; mt < 4; mt++)
            #pragma unroll
            for (int r = 0; r < 4; r++) {
                float v0 = acc0[mt][r], v1 = acc1[mt][r];
                float m = fmaxf(v0, v1);
                m = fmaxf(m, __shfl_xor(m, 1)); m = fmaxf(m, __shfl_xor(m, 2));
                m = fmaxf(m, __shfl_xor(m, 4)); m = fmaxf(m, __shfl_xor(m, 8));
                float e0 = __expf(v0 - m), e1 = __expf(v1 - m);
                float s = e0 + e1;
                s += __shfl_xor(s, 1); s += __shfl_xor(s, 2);
                s += __shfl_xor(s, 4); s += __shfl_xor(s, 8);
                float inv = 1.f / s;
                acc0[mt][r] = e0 * inv; acc1[mt][r] = e1 * inv;
            }
    }

    if (role == 0) {
        #pragma unroll
        for (int mt = 0; mt < 4; mt++)
            #pragma unroll
            for (int r = 0; r < 4; r++) {
                int row = mt * 16 + qg * 4 + r;
                int d0 = lr, d1 = 16 + lr;
                *(short*)(tile + row * 128 + (((d0 >> 3) ^ (row & 7)) << 4) + (d0 & 7) * 2) = (short)f2bf(acc0[mt][r]);
                *(short*)(tile + row * 128 + (((d1 >> 3) ^ (row & 7)) << 4) + (d1 & 7) * 2) = (short)f2bf(acc1[mt][r]);
            }
    } else if (role == 1) {
        #pragma unroll
        for (int mt = 0; mt < 4; mt++)
            #pragma unroll
            for (int r = 0; r < 4; r++) {
                int row = mt * 16 + qg * 4 + r;
                int d0 = lr, d1 = 16 + lr;
                *(short*)(tile + 8192 + row * 128 + (((d0 >> 3) ^ (row & 7)) << 4) + (d0 & 7) * 2) = (short)f2bf(acc0[mt][r]);
                *(short*)(tile + 8192 + row * 128 + (((d1 >> 3) ^ (row & 7)) << 4) + (d1 & 7) * 2) = (short)f2bf(acc1[mt][r]);
            }
    } else {
        const int d = (role - 2) * 16 + lr;
        #pragma unroll
        for (int mt = 0; mt < 4; mt++)
            #pragma unroll
            for (int r = 0; r < 4; r++) {
                int row = mt * 16 + qg * 4 + r;
                *(short*)(tile + 16384 + d * 128 + (((row >> 3) ^ (d & 7)) << 4) + (row & 7) * 2) = (short)f2bf(acc0[mt][r]);
            }
    }
    __syncthreads();

    {
        bf16x8 aqf = *(const bf16x8*)(tile + (w * 16 + lr) * 128 + ((qg ^ (lr & 7)) << 4));
        const float* bh_ = biasws + h * 4096;
        #pragma unroll
        for (int jt = 0; jt < 4; jt++) {
            bf16x8 bkf = *(const bf16x8*)(tile + 8192 + (jt * 16 + lr) * 128 + ((qg ^ (lr & 7)) << 4));
            f32x4 sc = {0.f, 0.f, 0.f, 0.f};
            sc = __builtin_amdgcn_mfma_f32_16x16x32_bf16(aqf, bkf, sc, 0, 0, 0);
            #pragma unroll
            for (int r = 0; r < 4; r++) {
                int i = w * 16 + qg * 4 + r, j = jt * 16 + lr;
                As[i * AST + j] = sc[r] + bh_[i * 64 + j];
            }
        }
    }
    __syncthreads();

    {
        int j = t & 63, i0 = (t >> 6) * 16;
        float sij[16], sji[16];
        #pragma unroll
        for (int rr = 0; rr < 16; rr++) { sij[rr] = As[(i0 + rr) * AST + j]; sji[rr] = As[j * AST + i0 + rr]; }
        __syncthreads();
        #pragma unroll
        for (int rr = 0; rr < 16; rr++) As[(i0 + rr) * AST + j] = 0.5f * (sij[rr] + sji[rr]);
    }
    __syncthreads();

    if (t < 64) {
        float s = 0.f;
        #pragma unroll
        for (int k4 = 0; k4 < 16; k4++) {
            float4 v4 = *(const float4*)&As[t * AST + k4 * 4];
            s += v4.x + v4.y + v4.z + v4.w;
        }
        dn[t] = (s > 0.f) ? rsqrtf(s) : s;
    }
    __syncthreads();

    {
        int i = t >> 2, j0 = (t & 3) * 16;
        float di = dn[i];
        float vals[16];
        #pragma unroll
        for (int e4 = 0; e4 < 4; e4++) {
            float4 v4 = *(const float4*)&As[i * AST + j0 + e4 * 4];
            float4 d4 = *(const float4*)&dn[j0 + e4 * 4];
            vals[e4 * 4 + 0] = v4.x * di * d4.x;
            vals[e4 * 4 + 1] = v4.y * di * d4.y;
            vals[e4 * 4 + 2] = v4.z * di * d4.z;
            vals[e4 * 4 + 3] = v4.w * di * d4.w;
        }
        uint4 u0, u1;
        u0.x = pk2(vals[0], vals[1]);   u0.y = pk2(vals[2], vals[3]);
        u0.z = pk2(vals[4], vals[5]);   u0.w = pk2(vals[6], vals[7]);
        u1.x = pk2(vals[8], vals[9]);   u1.y = pk2(vals[10], vals[11]);
        u1.z = pk2(vals[12], vals[13]); u1.w = pk2(vals[14], vals[15]);
        int c0 = (t & 3) * 2;
        *(uint4*)(tile + i * 128 + (((c0) ^ (i & 7)) << 4)) = u0;
        *(uint4*)(tile + i * 128 + (((c0 + 1) ^ (i & 7)) << 4)) = u1;
    }
    __syncthreads();

    const float w0c = wv4.x, w1c = wv4.y, w2c = wv4.z, w3c = wv4.w;
    f32x4 y[2];
    #pragma unroll
    for (int ct = 0; ct < 2; ct++)
        #pragma unroll
        for (int r = 0; r < 4; r++) {
            int row = w * 16 + qg * 4 + r;
            int d = ct * 16 + lr;
            unsigned short us = *(unsigned short*)(tile + 16384 + d * 128 + (((row >> 3) ^ (d & 7)) << 4) + (row & 7) * 2);
            y[ct][r] = w0c * bf2f(us);
        }

#define AU_ROUND(SRC, DST, WC, WRITE) {                                                          \
    f32x4 u0 = {0.f,0.f,0.f,0.f}, u1 = {0.f,0.f,0.f,0.f};                                        \
    _Pragma("unroll")                                                                            \
    for (int ks2 = 0; ks2 < 2; ks2++) {                                                          \
        int c = ks2 * 4 + qg;                                                                    \
        bf16x8 af = *(const bf16x8*)(tile + (w * 16 + lr) * 128 + ((c ^ (lr & 7)) << 4));        \
        bf16x8 b0 = *(const bf16x8*)(tile + (SRC) + lr * 128 + ((c ^ (lr & 7)) << 4));           \
        bf16x8 b1 = *(const bf16x8*)(tile + (SRC) + (16 + lr) * 128 + ((c ^ (lr & 7)) << 4));    \
        u0 = __builtin_amdgcn_mfma_f32_16x16x32_bf16(af, b0, u0, 0, 0, 0);                       \
        u1 = __builtin_amdgcn_mfma_f32_16x16x32_bf16(af, b1, u1, 0, 0, 0);                       \
    }                                                                                            \
    y[0] += (WC) * u0; y[1] += (WC) * u1;                                                        \
    if (WRITE) {                                                                                 \
        _Pragma("unroll")                                                                        \
        for (int r = 0; r < 4; r++) {                                                            \
            int i = w * 16 + qg * 4 + r;                                                         \
            *(short*)(tile + (DST) + lr * 128 + (((i >> 3) ^ (lr & 7)) << 4) + (i & 7) * 2) = (short)f2bf(u0[r]); \
            *(short*)(tile + (DST) + (16 + lr) * 128 + (((i >> 3) ^ (lr & 7)) << 4) + (i & 7) * 2) = (short)f2bf(u1[r]); \
        }                                                                                        \
    }                                                                                            \
    __syncthreads();                                                                             \
}
    AU_ROUND(16384, 20480, w1c, 1)
    AU_ROUND(20480, 24576, w2c, 1)
    AU_ROUND(24576, 0,     w3c, 0)
#undef AU_ROUND

    #pragma unroll
    for (int ct = 0; ct < 2; ct++)
        #pragma unroll
        for (int r = 0; r < 4; r++) {
            int row = w * 16 + qg * 4 + r;
            int col = h * 32 + ct * 16 + lr;
            hid[((size_t)b * 64 + row) * 256 + col] = f2bf(y[ct][r]);
        }
}

// ===================== output projection: 128 x 256 tile, hidden read once =====================
__global__ __launch_bounds__(256) void proj_kernel(
    const unsigned short* __restrict__ hidden,
    const unsigned short* __restrict__ wp,
    const float* __restrict__ bproj,
    float* __restrict__ out)
{
    __shared__ __align__(16) unsigned char atile[65536];
    const int rb = blockIdx.x;
    const int t = threadIdx.x, l = t & 63, w = t >> 6;
    const int lr = l & 15, qg = l >> 4;

    const unsigned short* hb = hidden + (size_t)rb * 128 * 256;
    {
        const int rp = l >> 5, u = l & 31;
        #pragma unroll
        for (int i = 0; i < 16; i++) {
            int row = i * 8 + w * 2 + rp;
            int csrc = (u & 24) | ((u & 7) ^ (row & 7));
            gload_lds16(hb + row * 256 + csrc * 8, atile + (i * 8 + w * 2) * 512);
        }
    }
    float bzv[16];
    #pragma unroll
    for (int ct = 0; ct < 16; ct++) bzv[ct] = bproj[ct * 16 + lr];
    __syncthreads();

    // hoist A fragments: 2 row-tiles x 8 k-steps
    bf16x8 af[2][8];
    #pragma unroll
    for (int rt = 0; rt < 2; rt++) {
        int row = w * 32 + rt * 16 + lr;
        #pragma unroll
        for (int ks = 0; ks < 8; ks++) {
            int c = ks * 4 + qg;
            af[rt][ks] = *(const bf16x8*)(atile + row * 512 + (((c & 24) | ((c & 7) ^ (row & 7))) << 4));
        }
    }

    const uint4* WP = (const uint4*)wp;
    #pragma unroll 2
    for (int ct = 0; ct < 16; ct++) {
        f32x4 a0 = {0.f, 0.f, 0.f, 0.f}, a1 = {0.f, 0.f, 0.f, 0.f};
        #pragma unroll
        for (int ks = 0; ks < 8; ks++) {
            bf16x8 bf = as_bf(WP[(ct * 16 + lr) * 32 + ks * 4 + qg]);
            a0 = __builtin_amdgcn_mfma_f32_16x16x32_bf16(af[0][ks], bf, a0, 0, 0, 0);
            a1 = __builtin_amdgcn_mfma_f32_16x16x32_bf16(af[1][ks], bf, a1, 0, 0, 0);
        }
        int colg = ct * 16 + lr;
        float bz = bzv[ct];
        #pragma unroll
        for (int r = 0; r < 4; r++) {
            int rowg = rb * 128 + w * 32 + qg * 4 + r;
            out[(size_t)rowg * 256 + colg] = a0[r] + bz;
            out[(size_t)(rowg + 16) * 256 + colg] = a1[r] + bz;
        }
    }
}

extern "C" void kernel_launch(void* const* d_in, const int* in_sizes, int n_in,
                              void* d_out, int out_size, void* d_ws, size_t ws_size,
                              hipStream_t stream) {
    const float* x          = (const float*)d_in[0];
    const float* Wq         = (const float*)d_in[1];
    const float* bq         = (const float*)d_in[2];
    const float* Wkv        = (const float*)d_in[3];
    const float* bkv        = (const float*)d_in[4];
    const float* Wgate      = (const float*)d_in[5];
    const float* bgate      = (const float*)d_in[6];
    const float* Wproj      = (const float*)d_in[7];
    const float* bproj      = (const float*)d_in[8];
    const float* bias_table = (const float*)d_in[9];
    const int*   rel_index  = (const int*)d_in[10];
    float* out = (float*)d_out;
    unsigned char* wsb = (unsigned char*)d_ws;

    // ws layout (bytes)
    const size_t HID   = 0;                    // 33,554,432 (hidden bf16)
    const size_t WQo   = 33554432;             // 131072 each
    const size_t WKo   = WQo + 131072;
    const size_t WVo   = WKo + 131072;
    const size_t WPo   = WVo + 131072;
    const size_t BIASo = WPo + 131072;         // 131072
    const size_t WPOLY = BIASo + 131072;       // 131072
    const size_t XBFo  = WPOLY + 131072;       // 33,554,432 (x bf16) — optional
    const int use_xbf  = (ws_size >= XBFo + 33554432ull) ? 1 : 0;

    unsigned short* hid = (unsigned short*)(wsb + HID);
    unsigned short* wq  = (unsigned short*)(wsb + WQo);
    unsigned short* wk  = (unsigned short*)(wsb + WKo);
    unsigned short* wv  = (unsigned short*)(wsb + WVo);
    unsigned short* wp  = (unsigned short*)(wsb + WPo);
    float* biasws = (float*)(wsb + BIASo);
    float* wpoly  = (float*)(wsb + WPOLY);
    unsigned short* xbf = (unsigned short*)(wsb + XBFo);

    prep_kernel<<<dim3(2176), dim3(256), 0, stream>>>(
        x, Wq, Wkv, Wproj, Wgate, bgate, bias_table, rel_index,
        xbf, use_xbf, wq, wk, wv, wp, biasws, wpoly);
    if (use_xbf)
        attn2_kernel<true><<<dim3(8192), dim3(256), 0, stream>>>(
            x, xbf, bq, bkv, wq, wk, wv, biasws, wpoly, hid);
    else
        attn2_kernel<false><<<dim3(8192), dim3(256), 0, stream>>>(
            x, xbf, bq, bkv, wq, wk, wv, biasws, wpoly, hid);
    proj_kernel<<<dim3(512), dim3(256), 0, stream>>>(hid, wp, bproj, out);
}

// Round 5
// 173.971 us; speedup vs baseline: 5.3122x; 1.0240x over previous
//
#include <hip/hip_runtime.h>
#include <hip/hip_bf16.h>

typedef __attribute__((ext_vector_type(8))) short bf16x8;
typedef __attribute__((ext_vector_type(4))) float f32x4;

__device__ __forceinline__ unsigned short f2bf(float f) {
    union { __hip_bfloat16 h; unsigned short u; } c;
    c.h = __float2bfloat16(f);
    return c.u;
}
__device__ __forceinline__ unsigned int pk2(float lo, float hi) {
    return (unsigned int)f2bf(lo) | ((unsigned int)f2bf(hi) << 16);
}
__device__ __forceinline__ bf16x8 as_bf(uint4 u) {
    union { uint4 a; bf16x8 b; } c; c.a = u; return c.b;
}
__device__ __forceinline__ float bf2f(unsigned short us) {
    return __uint_as_float(((unsigned int)us) << 16);
}
// async global->LDS, 16B/lane; lds dest = wave-uniform base + lane*16 (HW rule)
__device__ __forceinline__ void gload_lds16(const void* g, void* l) {
    __builtin_amdgcn_global_load_lds(
        (const __attribute__((address_space(1))) void*)g,
        (__attribute__((address_space(3))) void*)l, 16, 0, 0);
}

// ===================== prep: x->bf16 + means + gate/poly, weight pack, sym-bias =====================
__global__ __launch_bounds__(256) void prep_kernel(
    const float* __restrict__ x,
    const float* __restrict__ Wq, const float* __restrict__ Wkv, const float* __restrict__ Wproj,
    const float* __restrict__ Wgate, const float* __restrict__ bgate,
    const float* __restrict__ bias_table, const int* __restrict__ rel_index,
    unsigned short* __restrict__ xbf, int use_xbf,
    unsigned short* __restrict__ wq, unsigned short* __restrict__ wk,
    unsigned short* __restrict__ wv, unsigned short* __restrict__ wp,
    float* __restrict__ bsym, float* __restrict__ wpoly)
{
    const int bid = blockIdx.x, t = threadIdx.x;
    if (bid < 1024) {
        __shared__ float mean_s[256];
        __shared__ float gsig[32];
        const float* xb = x + (size_t)bid * 16384;
        float s = 0.f;
        if (use_xbf) {
            unsigned short* xo = xbf + (size_t)bid * 16384;
            #pragma unroll 4
            for (int n = 0; n < 64; n++) { float v = xb[n * 256 + t]; s += v; xo[n * 256 + t] = f2bf(v); }
        } else {
            #pragma unroll 8
            for (int n = 0; n < 64; n++) s += xb[n * 256 + t];
        }
        mean_s[t] = s * (1.f / 64.f);
        __syncthreads();
        if (t < 32) {
            int h = t >> 2, j = t & 3;
            float g = bgate[j];
            #pragma unroll 8
            for (int dd = 0; dd < 32; dd++) g = fmaf(mean_s[h * 32 + dd], Wgate[dd * 4 + j], g);
            gsig[t] = 1.f / (1.f + __expf(-g));
        }
        __syncthreads();
        if (t < 8) {
            float g0 = gsig[t * 4], g1 = gsig[t * 4 + 1], g2 = gsig[t * 4 + 2], g3 = gsig[t * 4 + 3];
            float a = 0.125f * g3, bb = 0.375f * g0, cc = 0.375f * g1, dd = 0.125f * g2;
            float4 o;
            o.x = a + bb + cc + dd;
            o.y = 3.f * a + bb - cc - 3.f * dd;
            o.z = 3.f * a - bb - cc + 3.f * dd;
            o.w = a - bb + cc - dd;
            ((float4*)wpoly)[bid * 8 + t] = o;
        }
    } else if (bid < 2048) {
        // transpose-pack 4 weight matrices to bf16: dst[o][k] = src[k][o]
        int e = (bid - 1024) * 256 + t;
        int m = e >> 16, r = e & 65535, o = r >> 8, kk = r & 255;
        float v; unsigned short* dst;
        if (m == 0)      { v = Wq[kk * 256 + o];        dst = wq; }
        else if (m == 1) { v = Wkv[kk * 512 + o];       dst = wk; }
        else if (m == 2) { v = Wkv[kk * 512 + 256 + o]; dst = wv; }
        else             { v = Wproj[kk * 256 + o];     dst = wp; }
        dst[o * 256 + kk] = f2bf(v);
    } else {
        // symmetric pre-relu positional bias: bsym[h][i*64+j] = (relu(b_ij)+relu(b_ji))/2
        int e = (bid - 2048) * 256 + t;
        int hh = e >> 12, ij = e & 4095;
        int i = ij >> 6, j = ij & 63;
        float bij = bias_table[rel_index[ij] * 8 + hh];
        float bji = bias_table[rel_index[j * 64 + i] * 8 + hh];
        bsym[hh * 4096 + ij] = 0.5f * (fmaxf(bij, 0.f) + fmaxf(bji, 0.f));
    }
}

// ===================== attention core =====================
// block = one (b,h); 4 waves, QKV role split: w0=q, w1=k, w2/w3=v halves.
// XCD-chunked swizzle: xcd=bid&7 owns b in [xcd*128, xcd*128+128), heads adjacent.
// LDS = exactly 32 KB -> 5 blocks/CU.
// tile regions (bytes): phase1 xs [64 rows][512B] swizzled (32 KB)
// overlay after QKV: Ab/q[0,8K); k[8K,16K); vT[16K,20K); ua[20K,24K); ub[24K,28K); dn f32[64] @28672
template <bool XBF>
__global__ __launch_bounds__(256, 5) void attn_kernel(
    const float* __restrict__ x, const unsigned short* __restrict__ xbf,
    const float* __restrict__ bq, const float* __restrict__ bkv,
    const unsigned short* __restrict__ wq, const unsigned short* __restrict__ wk,
    const unsigned short* __restrict__ wv,
    const float* __restrict__ bsym, const float* __restrict__ wpoly,
    unsigned short* __restrict__ hid)
{
    __shared__ __align__(16) unsigned char tile[32768];
    float* dn = (float*)(tile + 28672);

    const int bid = blockIdx.x;
    const int xcd = bid & 7, idx = bid >> 3;
    const int b = xcd * 128 + (idx >> 3), h = idx & 7;
    const int t = threadIdx.x;
    const int l = t & 63, w = t >> 6;
    const int lr = l & 15, qg = l >> 4;

    const float4 wv4 = ((const float4*)wpoly)[b * 8 + h];

    // ---- hoist weight B-fragments (issued before staging) ----
    const int role = w;                      // 0=q, 1=k, 2=v(d 0..15), 3=v(d 16..31)
    uint4 Bfr0[8], Bfr1[8];
    {
        const unsigned short* wsel = (role == 0) ? wq : (role == 1) ? wk : wv;
        const uint4* Wp = (const uint4*)wsel;
        const int ct0 = (role < 2) ? 0 : (role - 2);
        const int o0 = h * 32 + ct0 * 16 + lr;
        #pragma unroll
        for (int ks = 0; ks < 8; ks++) Bfr0[ks] = Wp[o0 * 32 + ks * 4 + qg];
        if (role < 2) {
            #pragma unroll
            for (int ks = 0; ks < 8; ks++) Bfr1[ks] = Wp[(o0 + 16) * 32 + ks * 4 + qg];
        }
    }

    // ---- phase 1: stage x[b] -> swizzled bf16 LDS ----
    if (XBF) {
        const unsigned short* xb = xbf + (size_t)b * 16384;
        const int rp = l >> 5, u = l & 31;
        #pragma unroll
        for (int i = 0; i < 8; i++) {
            int row = i * 8 + w * 2 + rp;
            int csrc = (u & 24) | ((u & 7) ^ (row & 7));   // inverse of reader swizzle (involution)
            gload_lds16(xb + row * 256 + csrc * 8, tile + (i * 8 + w * 2) * 512);
        }
    } else {
        const float* xb = x + (size_t)b * 16384;
        #pragma unroll
        for (int i = 0; i < 8; i++) {
            int e = t + i * 256;
            int row = e >> 5, c = e & 31;
            const float4* p = (const float4*)(xb + row * 256 + c * 8);
            float4 f0 = p[0], f1 = p[1];
            uint4 u;
            u.x = pk2(f0.x, f0.y); u.y = pk2(f0.z, f0.w);
            u.z = pk2(f1.x, f1.y); u.w = pk2(f1.z, f1.w);
            *(uint4*)(tile + row * 512 + ((c >> 3) << 7) + (((c & 7) ^ (row & 7)) << 4)) = u;
        }
    }

    // bias-init accumulators
    f32x4 acc0[4], acc1[4];
    {
        const int ct0 = (role < 2) ? 0 : (role - 2);
        const int o0 = h * 32 + ct0 * 16 + lr;
        float b0 = (role == 0) ? bq[o0] : (role == 1) ? bkv[o0] : bkv[256 + o0];
        float b1 = (role == 0) ? bq[o0 + 16] : (role == 1) ? bkv[o0 + 16] : 0.f;
        #pragma unroll
        for (int mt = 0; mt < 4; mt++) {
            f32x4 z0 = {b0, b0, b0, b0}; acc0[mt] = z0;
            f32x4 z1 = {b1, b1, b1, b1}; acc1[mt] = z1;
        }
    }
    __syncthreads();   // A: x-tile staged

    // ---- phase 2: QKV MFMA, zero global loads in loop ----
    if (role < 2) {
        #pragma unroll
        for (int mt = 0; mt < 4; mt++) {
            const int rowA = mt * 16 + lr;
            #pragma unroll
            for (int ks = 0; ks < 8; ks++) {
                const int c = ks * 4 + qg;
                bf16x8 af = *(const bf16x8*)(tile + rowA * 512 + ((c >> 3) << 7) + (((c & 7) ^ (rowA & 7)) << 4));
                acc0[mt] = __builtin_amdgcn_mfma_f32_16x16x32_bf16(af, as_bf(Bfr0[ks]), acc0[mt], 0, 0, 0);
                acc1[mt] = __builtin_amdgcn_mfma_f32_16x16x32_bf16(af, as_bf(Bfr1[ks]), acc1[mt], 0, 0, 0);
            }
        }
    } else {
        #pragma unroll
        for (int mt = 0; mt < 4; mt++) {
            const int rowA = mt * 16 + lr;
            #pragma unroll
            for (int ks = 0; ks < 8; ks++) {
                const int c = ks * 4 + qg;
                bf16x8 af = *(const bf16x8*)(tile + rowA * 512 + ((c >> 3) << 7) + (((c & 7) ^ (rowA & 7)) << 4));
                acc0[mt] = __builtin_amdgcn_mfma_f32_16x16x32_bf16(af, as_bf(Bfr0[ks]), acc0[mt], 0, 0, 0);
            }
        }
    }
    __syncthreads();   // B: all reads of x-tile done

    // hoist bsym loads (L2-latency hides under softmax+spill)
    float bsv[4][4];
    {
        const float* bh_ = bsym + h * 4096;
        #pragma unroll
        for (int jt = 0; jt < 4; jt++)
            #pragma unroll
            for (int r = 0; r < 4; r++)
                bsv[jt][r] = bh_[(w * 16 + qg * 4 + r) * 64 + jt * 16 + lr];
    }

    // ---- phase 3: row softmax for q (wave0) / k (wave1), no max-subtraction ----
    if (role < 2) {
        #pragma unroll
        for (int mt = 0; mt < 4; mt++)
            #pragma unroll
            for (int r = 0; r < 4; r++) {
                float e0 = __expf(acc0[mt][r]), e1 = __expf(acc1[mt][r]);
                float s = e0 + e1;
                s += __shfl_xor(s, 1); s += __shfl_xor(s, 2);
                s += __shfl_xor(s, 4); s += __shfl_xor(s, 8);
                float inv = 1.f / s;
                acc0[mt][r] = e0 * inv; acc1[mt][r] = e1 * inv;
            }
    }

    // ---- phase 4: spill q,k (row-major swizzled) and vT ----
    if (role == 0) {
        #pragma unroll
        for (int mt = 0; mt < 4; mt++)
            #pragma unroll
            for (int r = 0; r < 4; r++) {
                int row = mt * 16 + qg * 4 + r;
                int d0 = lr, d1 = 16 + lr;
                *(short*)(tile + row * 128 + (((d0 >> 3) ^ (row & 7)) << 4) + (d0 & 7) * 2) = (short)f2bf(acc0[mt][r]);
                *(short*)(tile + row * 128 + (((d1 >> 3) ^ (row & 7)) << 4) + (d1 & 7) * 2) = (short)f2bf(acc1[mt][r]);
            }
    } else if (role == 1) {
        #pragma unroll
        for (int mt = 0; mt < 4; mt++)
            #pragma unroll
            for (int r = 0; r < 4; r++) {
                int row = mt * 16 + qg * 4 + r;
                int d0 = lr, d1 = 16 + lr;
                *(short*)(tile + 8192 + row * 128 + (((d0 >> 3) ^ (row & 7)) << 4) + (d0 & 7) * 2) = (short)f2bf(acc0[mt][r]);
                *(short*)(tile + 8192 + row * 128 + (((d1 >> 3) ^ (row & 7)) << 4) + (d1 & 7) * 2) = (short)f2bf(acc1[mt][r]);
            }
    } else {
        const int d = (role - 2) * 16 + lr;
        #pragma unroll
        for (int mt = 0; mt < 4; mt++)
            #pragma unroll
            for (int r = 0; r < 4; r++) {
                int row = mt * 16 + qg * 4 + r;
                *(short*)(tile + 16384 + d * 128 + (((row >> 3) ^ (d & 7)) << 4) + (row & 7) * 2) = (short)f2bf(acc0[mt][r]);
            }
    }
    __syncthreads();   // C: q,k,vT readable

    // ---- phase 5: S_sym = (qk^T + (qk^T)^T)/2 + bsym, fused row-sums -> dn ----
    float sv[4][4];
    float dnv[4];
    {
        const int swz = (qg ^ (lr & 7)) << 4;
        bf16x8 aqf = *(const bf16x8*)(tile + (w * 16 + lr) * 128 + swz);
        bf16x8 akf = *(const bf16x8*)(tile + 8192 + (w * 16 + lr) * 128 + swz);
        float rs[4] = {0.f, 0.f, 0.f, 0.f};
        #pragma unroll
        for (int jt = 0; jt < 4; jt++) {
            bf16x8 bqf = *(const bf16x8*)(tile + (jt * 16 + lr) * 128 + swz);
            bf16x8 bkf = *(const bf16x8*)(tile + 8192 + (jt * 16 + lr) * 128 + swz);
            f32x4 qk = {0.f, 0.f, 0.f, 0.f}, kq = {0.f, 0.f, 0.f, 0.f};
            qk = __builtin_amdgcn_mfma_f32_16x16x32_bf16(aqf, bkf, qk, 0, 0, 0);
            kq = __builtin_amdgcn_mfma_f32_16x16x32_bf16(akf, bqf, kq, 0, 0, 0);
            #pragma unroll
            for (int r = 0; r < 4; r++) {
                float v = 0.5f * (qk[r] + kq[r]) + bsv[jt][r];
                sv[jt][r] = v;
                rs[r] += v;
            }
        }
        #pragma unroll
        for (int r = 0; r < 4; r++) {
            float s = rs[r];
            s += __shfl_xor(s, 1); s += __shfl_xor(s, 2);
            s += __shfl_xor(s, 4); s += __shfl_xor(s, 8);
            dnv[r] = (s > 0.f) ? rsqrtf(s) : s;
        }
        if (lr == 0) {
            int base = w * 16 + qg * 4;
            dn[base + 0] = dnv[0]; dn[base + 1] = dnv[1];
            dn[base + 2] = dnv[2]; dn[base + 3] = dnv[3];
        }
    }
    __syncthreads();   // D: dn ready; q/k reads done -> Ab may overwrite q region

    // ---- phase 6: normalize in-register, spill Ab bf16 (overlays q region) ----
    {
        float dnj[4];
        #pragma unroll
        for (int jt = 0; jt < 4; jt++) dnj[jt] = dn[jt * 16 + lr];
        #pragma unroll
        for (int jt = 0; jt < 4; jt++)
            #pragma unroll
            for (int r = 0; r < 4; r++) {
                int i = w * 16 + qg * 4 + r, j = jt * 16 + lr;
                *(short*)(tile + i * 128 + (((j >> 3) ^ (i & 7)) << 4) + (j & 7) * 2)
                    = (short)f2bf(sv[jt][r] * dnv[r] * dnj[jt]);
            }
    }
    __syncthreads();   // E: Ab ready

    // ---- phase 7-9: y = w0 v + w1 Av + w2 A^2 v + w3 A^3 v ----
    const float w0c = wv4.x, w1c = wv4.y, w2c = wv4.z, w3c = wv4.w;
    f32x4 y[2];
    #pragma unroll
    for (int ct = 0; ct < 2; ct++)
        #pragma unroll
        for (int r = 0; r < 4; r++) {
            int row = w * 16 + qg * 4 + r;
            int d = ct * 16 + lr;
            unsigned short us = *(unsigned short*)(tile + 16384 + d * 128 + (((row >> 3) ^ (d & 7)) << 4) + (row & 7) * 2);
            y[ct][r] = w0c * bf2f(us);
        }

#define AU_ROUND(SRC, DST, WC, WRITE) {                                                          \
    f32x4 u0 = {0.f,0.f,0.f,0.f}, u1 = {0.f,0.f,0.f,0.f};                                        \
    _Pragma("unroll")                                                                            \
    for (int ks2 = 0; ks2 < 2; ks2++) {                                                          \
        int c = ks2 * 4 + qg;                                                                    \
        bf16x8 af = *(const bf16x8*)(tile + (w * 16 + lr) * 128 + ((c ^ (lr & 7)) << 4));        \
        bf16x8 b0 = *(const bf16x8*)(tile + (SRC) + lr * 128 + ((c ^ (lr & 7)) << 4));           \
        bf16x8 b1 = *(const bf16x8*)(tile + (SRC) + (16 + lr) * 128 + ((c ^ (lr & 7)) << 4));    \
        u0 = __builtin_amdgcn_mfma_f32_16x16x32_bf16(af, b0, u0, 0, 0, 0);                       \
        u1 = __builtin_amdgcn_mfma_f32_16x16x32_bf16(af, b1, u1, 0, 0, 0);                       \
    }                                                                                            \
    y[0] += (WC) * u0; y[1] += (WC) * u1;                                                        \
    if (WRITE) {                                                                                 \
        _Pragma("unroll")                                                                        \
        for (int r = 0; r < 4; r++) {                                                            \
            int i = w * 16 + qg * 4 + r;                                                         \
            *(short*)(tile + (DST) + lr * 128 + (((i >> 3) ^ (lr & 7)) << 4) + (i & 7) * 2) = (short)f2bf(u0[r]); \
            *(short*)(tile + (DST) + (16 + lr) * 128 + (((i >> 3) ^ (lr & 7)) << 4) + (i & 7) * 2) = (short)f2bf(u1[r]); \
        }                                                                                        \
    }                                                                                            \
    __syncthreads();                                                                             \
}
    AU_ROUND(16384, 20480, w1c, 1)   // u1 = A v   -> ua
    AU_ROUND(20480, 24576, w2c, 1)   // u2 = A u1  -> ub
    AU_ROUND(24576, 0,     w3c, 0)   // u3 = A u2
#undef AU_ROUND

    // ---- write hidden bf16 ----
    #pragma unroll
    for (int ct = 0; ct < 2; ct++)
        #pragma unroll
        for (int r = 0; r < 4; r++) {
            int row = w * 16 + qg * 4 + r;
            int col = h * 32 + ct * 16 + lr;
            hid[((size_t)b * 64 + row) * 256 + col] = f2bf(y[ct][r]);
        }
}

// ===================== output projection: 128 x 256 tile, hidden read once =====================
__global__ __launch_bounds__(256) void proj_kernel(
    const unsigned short* __restrict__ hidden,
    const unsigned short* __restrict__ wp,
    const float* __restrict__ bproj,
    float* __restrict__ out)
{
    __shared__ __align__(16) unsigned char atile[65536];
    const int rb = blockIdx.x;
    const int t = threadIdx.x, l = t & 63, w = t >> 6;
    const int lr = l & 15, qg = l >> 4;

    const unsigned short* hb = hidden + (size_t)rb * 128 * 256;
    {
        const int rp = l >> 5, u = l & 31;
        #pragma unroll
        for (int i = 0; i < 16; i++) {
            int row = i * 8 + w * 2 + rp;
            int csrc = (u & 24) | ((u & 7) ^ (row & 7));
            gload_lds16(hb + row * 256 + csrc * 8, atile + (i * 8 + w * 2) * 512);
        }
    }
    float bzv[16];
    #pragma unroll
    for (int ct = 0; ct < 16; ct++) bzv[ct] = bproj[ct * 16 + lr];
    __syncthreads();

    // hoist A fragments: 2 row-tiles x 8 k-steps
    bf16x8 af[2][8];
    #pragma unroll
    for (int rt = 0; rt < 2; rt++) {
        int row = w * 32 + rt * 16 + lr;
        #pragma unroll
        for (int ks = 0; ks < 8; ks++) {
            int c = ks * 4 + qg;
            af[rt][ks] = *(const bf16x8*)(atile + row * 512 + (((c & 24) | ((c & 7) ^ (row & 7))) << 4));
        }
    }

    const uint4* WP = (const uint4*)wp;
    #pragma unroll 2
    for (int ct = 0; ct < 16; ct++) {
        f32x4 a0 = {0.f, 0.f, 0.f, 0.f}, a1 = {0.f, 0.f, 0.f, 0.f};
        #pragma unroll
        for (int ks = 0; ks < 8; ks++) {
            bf16x8 bf = as_bf(WP[(ct * 16 + lr) * 32 + ks * 4 + qg]);
            a0 = __builtin_amdgcn_mfma_f32_16x16x32_bf16(af[0][ks], bf, a0, 0, 0, 0);
            a1 = __builtin_amdgcn_mfma_f32_16x16x32_bf16(af[1][ks], bf, a1, 0, 0, 0);
        }
        int colg = ct * 16 + lr;
        float bz = bzv[ct];
        #pragma unroll
        for (int r = 0; r < 4; r++) {
            int rowg = rb * 128 + w * 32 + qg * 4 + r;
            out[(size_t)rowg * 256 + colg] = a0[r] + bz;
            out[(size_t)(rowg + 16) * 256 + colg] = a1[r] + bz;
        }
    }
}

extern "C" void kernel_launch(void* const* d_in, const int* in_sizes, int n_in,
                              void* d_out, int out_size, void* d_ws, size_t ws_size,
                              hipStream_t stream) {
    const float* x          = (const float*)d_in[0];
    const float* Wq         = (const float*)d_in[1];
    const float* bq         = (const float*)d_in[2];
    const float* Wkv        = (const float*)d_in[3];
    const float* bkv        = (const float*)d_in[4];
    const float* Wgate      = (const float*)d_in[5];
    const float* bgate      = (const float*)d_in[6];
    const float* Wproj      = (const float*)d_in[7];
    const float* bproj      = (const float*)d_in[8];
    const float* bias_table = (const float*)d_in[9];
    const int*   rel_index  = (const int*)d_in[10];
    float* out = (float*)d_out;
    unsigned char* wsb = (unsigned char*)d_ws;

    // ws layout (bytes)
    const size_t HID   = 0;                    // 33,554,432 (hidden bf16)
    const size_t WQo   = 33554432;             // 131072 each
    const size_t WKo   = WQo + 131072;
    const size_t WVo   = WKo + 131072;
    const size_t WPo   = WVo + 131072;
    const size_t BIASo = WPo + 131072;         // 131072 (bsym f32 [8][64][64])
    const size_t WPOLY = BIASo + 131072;       // 131072
    const size_t XBFo  = WPOLY + 131072;       // 33,554,432 (x bf16) — optional
    const int use_xbf  = (ws_size >= XBFo + 33554432ull) ? 1 : 0;

    unsigned short* hid = (unsigned short*)(wsb + HID);
    unsigned short* wq  = (unsigned short*)(wsb + WQo);
    unsigned short* wk  = (unsigned short*)(wsb + WKo);
    unsigned short* wv  = (unsigned short*)(wsb + WVo);
    unsigned short* wp  = (unsigned short*)(wsb + WPo);
    float* bsym  = (float*)(wsb + BIASo);
    float* wpoly = (float*)(wsb + WPOLY);
    unsigned short* xbf = (unsigned short*)(wsb + XBFo);

    prep_kernel<<<dim3(2176), dim3(256), 0, stream>>>(
        x, Wq, Wkv, Wproj, Wgate, bgate, bias_table, rel_index,
        xbf, use_xbf, wq, wk, wv, wp, bsym, wpoly);
    if (use_xbf)
        attn_kernel<true><<<dim3(8192), dim3(256), 0, stream>>>(
            x, xbf, bq, bkv, wq, wk, wv, bsym, wpoly, hid);
    else
        attn_kernel<false><<<dim3(8192), dim3(256), 0, stream>>>(
            x, xbf, bq, bkv, wq, wk, wv, bsym, wpoly, hid);
    proj_kernel<<<dim3(512), dim3(256), 0, stream>>>(hid, wp, bproj, out);
}

// Round 6
// 142.492 us; speedup vs baseline: 6.4858x; 1.2209x over previous
//
#include <hip/hip_runtime.h>
#include <hip/hip_bf16.h>

typedef __attribute__((ext_vector_type(8))) short bf16x8;
typedef __attribute__((ext_vector_type(4))) float f32x4;

__device__ __forceinline__ unsigned short f2bf(float f) {
    union { __hip_bfloat16 h; unsigned short u; } c;
    c.h = __float2bfloat16(f);
    return c.u;
}
__device__ __forceinline__ unsigned int pk2(float lo, float hi) {
    return (unsigned int)f2bf(lo) | ((unsigned int)f2bf(hi) << 16);
}
__device__ __forceinline__ bf16x8 as_bf(uint4 u) {
    union { uint4 a; bf16x8 b; } c; c.a = u; return c.b;
}
__device__ __forceinline__ float bf2f(unsigned short us) {
    return __uint_as_float(((unsigned int)us) << 16);
}
// async global->LDS, 16B/lane; lds dest = wave-uniform base + lane*16 (HW rule)
__device__ __forceinline__ void gload_lds16(const void* g, void* l) {
    __builtin_amdgcn_global_load_lds(
        (const __attribute__((address_space(1))) void*)g,
        (__attribute__((address_space(3))) void*)l, 16, 0, 0);
}

// ===================== prep: x->bf16 + means + gate/poly, weight pack, sym-bias =====================
__global__ __launch_bounds__(256) void prep_kernel(
    const float* __restrict__ x,
    const float* __restrict__ Wq, const float* __restrict__ Wkv, const float* __restrict__ Wproj,
    const float* __restrict__ Wgate, const float* __restrict__ bgate,
    const float* __restrict__ bias_table, const int* __restrict__ rel_index,
    unsigned short* __restrict__ xbf, int use_xbf,
    unsigned short* __restrict__ wq, unsigned short* __restrict__ wk,
    unsigned short* __restrict__ wv, unsigned short* __restrict__ wp,
    float* __restrict__ bsym, float* __restrict__ wpoly)
{
    const int bid = blockIdx.x, t = threadIdx.x;
    if (bid < 1024) {
        __shared__ float mean_s[256];
        __shared__ float gsig[32];
        const float* xb = x + (size_t)bid * 16384;
        float s = 0.f;
        if (use_xbf) {
            unsigned short* xo = xbf + (size_t)bid * 16384;
            #pragma unroll 4
            for (int n = 0; n < 64; n++) { float v = xb[n * 256 + t]; s += v; xo[n * 256 + t] = f2bf(v); }
        } else {
            #pragma unroll 8
            for (int n = 0; n < 64; n++) s += xb[n * 256 + t];
        }
        mean_s[t] = s * (1.f / 64.f);
        __syncthreads();
        if (t < 32) {
            int h = t >> 2, j = t & 3;
            float g = bgate[j];
            #pragma unroll 8
            for (int dd = 0; dd < 32; dd++) g = fmaf(mean_s[h * 32 + dd], Wgate[dd * 4 + j], g);
            gsig[t] = 1.f / (1.f + __expf(-g));
        }
        __syncthreads();
        if (t < 8) {
            float g0 = gsig[t * 4], g1 = gsig[t * 4 + 1], g2 = gsig[t * 4 + 2], g3 = gsig[t * 4 + 3];
            float a = 0.125f * g3, bb = 0.375f * g0, cc = 0.375f * g1, dd = 0.125f * g2;
            float4 o;
            o.x = a + bb + cc + dd;
            o.y = 3.f * a + bb - cc - 3.f * dd;
            o.z = 3.f * a - bb - cc + 3.f * dd;
            o.w = a - bb + cc - dd;
            ((float4*)wpoly)[bid * 8 + t] = o;
        }
    } else if (bid < 2048) {
        // transpose-pack 4 weight matrices to bf16: dst[o][k] = src[k][o]
        int e = (bid - 1024) * 256 + t;
        int m = e >> 16, r = e & 65535, o = r >> 8, kk = r & 255;
        float v; unsigned short* dst;
        if (m == 0)      { v = Wq[kk * 256 + o];        dst = wq; }
        else if (m == 1) { v = Wkv[kk * 512 + o];       dst = wk; }
        else if (m == 2) { v = Wkv[kk * 512 + 256 + o]; dst = wv; }
        else             { v = Wproj[kk * 256 + o];     dst = wp; }
        dst[o * 256 + kk] = f2bf(v);
    } else {
        // symmetric pre-relu positional bias: bsym[h][i*64+j] = (relu(b_ij)+relu(b_ji))/2
        int e = (bid - 2048) * 256 + t;
        int hh = e >> 12, ij = e & 4095;
        int i = ij >> 6, j = ij & 63;
        float bij = bias_table[rel_index[ij] * 8 + hh];
        float bji = bias_table[rel_index[j * 64 + i] * 8 + hh];
        bsym[hh * 4096 + ij] = 0.5f * (fmaxf(bij, 0.f) + fmaxf(bji, 0.f));
    }
}

// ===================== attention core =====================
// block = one (b,h); 4 waves, QKV role split: w0=q, w1=k, w2/w3=v halves.
// XCD-chunked swizzle: xcd=bid&7 owns b in [xcd*128, xcd*128+128), heads adjacent.
// LDS = exactly 32 KB; launch_bounds(256,4): VGPR cap 128 >= ~115 peak -> NO spill
// (R5's (256,5) forced 48 VGPRs -> 232 MB scratch traffic).
// tile regions (bytes): phase1 xs [64 rows][512B] swizzled (32 KB)
// overlay after QKV: Ab/q[0,8K); k[8K,16K); vT[16K,20K); ua[20K,24K); ub[24K,28K); dn f32[64] @28672
template <bool XBF>
__global__ __launch_bounds__(256, 4) void attn_kernel(
    const float* __restrict__ x, const unsigned short* __restrict__ xbf,
    const float* __restrict__ bq, const float* __restrict__ bkv,
    const unsigned short* __restrict__ wq, const unsigned short* __restrict__ wk,
    const unsigned short* __restrict__ wv,
    const float* __restrict__ bsym, const float* __restrict__ wpoly,
    unsigned short* __restrict__ hid)
{
    __shared__ __align__(16) unsigned char tile[32768];
    float* dn = (float*)(tile + 28672);

    const int bid = blockIdx.x;
    const int xcd = bid & 7, idx = bid >> 3;
    const int b = xcd * 128 + (idx >> 3), h = idx & 7;
    const int t = threadIdx.x;
    const int l = t & 63, w = t >> 6;
    const int lr = l & 15, qg = l >> 4;

    const float4 wv4 = ((const float4*)wpoly)[b * 8 + h];

    // ---- hoist weight B-fragments (issued before staging) ----
    const int role = w;                      // 0=q, 1=k, 2=v(d 0..15), 3=v(d 16..31)
    uint4 Bfr0[8], Bfr1[8];
    {
        const unsigned short* wsel = (role == 0) ? wq : (role == 1) ? wk : wv;
        const uint4* Wp = (const uint4*)wsel;
        const int ct0 = (role < 2) ? 0 : (role - 2);
        const int o0 = h * 32 + ct0 * 16 + lr;
        #pragma unroll
        for (int ks = 0; ks < 8; ks++) Bfr0[ks] = Wp[o0 * 32 + ks * 4 + qg];
        if (role < 2) {
            #pragma unroll
            for (int ks = 0; ks < 8; ks++) Bfr1[ks] = Wp[(o0 + 16) * 32 + ks * 4 + qg];
        }
    }

    // ---- phase 1: stage x[b] -> swizzled bf16 LDS ----
    if (XBF) {
        const unsigned short* xb = xbf + (size_t)b * 16384;
        const int rp = l >> 5, u = l & 31;
        #pragma unroll
        for (int i = 0; i < 8; i++) {
            int row = i * 8 + w * 2 + rp;
            int csrc = (u & 24) | ((u & 7) ^ (row & 7));   // inverse of reader swizzle (involution)
            gload_lds16(xb + row * 256 + csrc * 8, tile + (i * 8 + w * 2) * 512);
        }
    } else {
        const float* xb = x + (size_t)b * 16384;
        #pragma unroll
        for (int i = 0; i < 8; i++) {
            int e = t + i * 256;
            int row = e >> 5, c = e & 31;
            const float4* p = (const float4*)(xb + row * 256 + c * 8);
            float4 f0 = p[0], f1 = p[1];
            uint4 u;
            u.x = pk2(f0.x, f0.y); u.y = pk2(f0.z, f0.w);
            u.z = pk2(f1.x, f1.y); u.w = pk2(f1.z, f1.w);
            *(uint4*)(tile + row * 512 + ((c >> 3) << 7) + (((c & 7) ^ (row & 7)) << 4)) = u;
        }
    }

    // bias-init accumulators
    f32x4 acc0[4], acc1[4];
    {
        const int ct0 = (role < 2) ? 0 : (role - 2);
        const int o0 = h * 32 + ct0 * 16 + lr;
        float b0 = (role == 0) ? bq[o0] : (role == 1) ? bkv[o0] : bkv[256 + o0];
        float b1 = (role == 0) ? bq[o0 + 16] : (role == 1) ? bkv[o0 + 16] : 0.f;
        #pragma unroll
        for (int mt = 0; mt < 4; mt++) {
            f32x4 z0 = {b0, b0, b0, b0}; acc0[mt] = z0;
            f32x4 z1 = {b1, b1, b1, b1}; acc1[mt] = z1;
        }
    }
    __syncthreads();   // A: x-tile staged

    // ---- phase 2: QKV MFMA, zero global loads in loop ----
    if (role < 2) {
        #pragma unroll
        for (int mt = 0; mt < 4; mt++) {
            const int rowA = mt * 16 + lr;
            #pragma unroll
            for (int ks = 0; ks < 8; ks++) {
                const int c = ks * 4 + qg;
                bf16x8 af = *(const bf16x8*)(tile + rowA * 512 + ((c >> 3) << 7) + (((c & 7) ^ (rowA & 7)) << 4));
                acc0[mt] = __builtin_amdgcn_mfma_f32_16x16x32_bf16(af, as_bf(Bfr0[ks]), acc0[mt], 0, 0, 0);
                acc1[mt] = __builtin_amdgcn_mfma_f32_16x16x32_bf16(af, as_bf(Bfr1[ks]), acc1[mt], 0, 0, 0);
            }
        }
    } else {
        #pragma unroll
        for (int mt = 0; mt < 4; mt++) {
            const int rowA = mt * 16 + lr;
            #pragma unroll
            for (int ks = 0; ks < 8; ks++) {
                const int c = ks * 4 + qg;
                bf16x8 af = *(const bf16x8*)(tile + rowA * 512 + ((c >> 3) << 7) + (((c & 7) ^ (rowA & 7)) << 4));
                acc0[mt] = __builtin_amdgcn_mfma_f32_16x16x32_bf16(af, as_bf(Bfr0[ks]), acc0[mt], 0, 0, 0);
            }
        }
    }
    __syncthreads();   // B: all reads of x-tile done

    // hoist bsym loads (L2-latency hides under softmax+spill)
    float bsv[4][4];
    {
        const float* bh_ = bsym + h * 4096;
        #pragma unroll
        for (int jt = 0; jt < 4; jt++)
            #pragma unroll
            for (int r = 0; r < 4; r++)
                bsv[jt][r] = bh_[(w * 16 + qg * 4 + r) * 64 + jt * 16 + lr];
    }

    // ---- phase 3: row softmax for q (wave0) / k (wave1), no max-subtraction ----
    if (role < 2) {
        #pragma unroll
        for (int mt = 0; mt < 4; mt++)
            #pragma unroll
            for (int r = 0; r < 4; r++) {
                float e0 = __expf(acc0[mt][r]), e1 = __expf(acc1[mt][r]);
                float s = e0 + e1;
                s += __shfl_xor(s, 1); s += __shfl_xor(s, 2);
                s += __shfl_xor(s, 4); s += __shfl_xor(s, 8);
                float inv = 1.f / s;
                acc0[mt][r] = e0 * inv; acc1[mt][r] = e1 * inv;
            }
    }

    // ---- phase 4: spill q,k (row-major swizzled) and vT ----
    if (role == 0) {
        #pragma unroll
        for (int mt = 0; mt < 4; mt++)
            #pragma unroll
            for (int r = 0; r < 4; r++) {
                int row = mt * 16 + qg * 4 + r;
                int d0 = lr, d1 = 16 + lr;
                *(short*)(tile + row * 128 + (((d0 >> 3) ^ (row & 7)) << 4) + (d0 & 7) * 2) = (short)f2bf(acc0[mt][r]);
                *(short*)(tile + row * 128 + (((d1 >> 3) ^ (row & 7)) << 4) + (d1 & 7) * 2) = (short)f2bf(acc1[mt][r]);
            }
    } else if (role == 1) {
        #pragma unroll
        for (int mt = 0; mt < 4; mt++)
            #pragma unroll
            for (int r = 0; r < 4; r++) {
                int row = mt * 16 + qg * 4 + r;
                int d0 = lr, d1 = 16 + lr;
                *(short*)(tile + 8192 + row * 128 + (((d0 >> 3) ^ (row & 7)) << 4) + (d0 & 7) * 2) = (short)f2bf(acc0[mt][r]);
                *(short*)(tile + 8192 + row * 128 + (((d1 >> 3) ^ (row & 7)) << 4) + (d1 & 7) * 2) = (short)f2bf(acc1[mt][r]);
            }
    } else {
        const int d = (role - 2) * 16 + lr;
        #pragma unroll
        for (int mt = 0; mt < 4; mt++)
            #pragma unroll
            for (int r = 0; r < 4; r++) {
                int row = mt * 16 + qg * 4 + r;
                *(short*)(tile + 16384 + d * 128 + (((row >> 3) ^ (d & 7)) << 4) + (row & 7) * 2) = (short)f2bf(acc0[mt][r]);
            }
    }
    __syncthreads();   // C: q,k,vT readable

    // ---- phase 5: S_sym = (qk^T + (qk^T)^T)/2 + bsym, fused row-sums -> dn ----
    float sv[4][4];
    float dnv[4];
    {
        const int swz = (qg ^ (lr & 7)) << 4;
        bf16x8 aqf = *(const bf16x8*)(tile + (w * 16 + lr) * 128 + swz);
        bf16x8 akf = *(const bf16x8*)(tile + 8192 + (w * 16 + lr) * 128 + swz);
        float rs[4] = {0.f, 0.f, 0.f, 0.f};
        #pragma unroll
        for (int jt = 0; jt < 4; jt++) {
            bf16x8 bqf = *(const bf16x8*)(tile + (jt * 16 + lr) * 128 + swz);
            bf16x8 bkf = *(const bf16x8*)(tile + 8192 + (jt * 16 + lr) * 128 + swz);
            f32x4 qk = {0.f, 0.f, 0.f, 0.f}, kq = {0.f, 0.f, 0.f, 0.f};
            qk = __builtin_amdgcn_mfma_f32_16x16x32_bf16(aqf, bkf, qk, 0, 0, 0);
            kq = __builtin_amdgcn_mfma_f32_16x16x32_bf16(akf, bqf, kq, 0, 0, 0);
            #pragma unroll
            for (int r = 0; r < 4; r++) {
                float v = 0.5f * (qk[r] + kq[r]) + bsv[jt][r];
                sv[jt][r] = v;
                rs[r] += v;
            }
        }
        #pragma unroll
        for (int r = 0; r < 4; r++) {
            float s = rs[r];
            s += __shfl_xor(s, 1); s += __shfl_xor(s, 2);
            s += __shfl_xor(s, 4); s += __shfl_xor(s, 8);
            dnv[r] = (s > 0.f) ? rsqrtf(s) : s;
        }
        if (lr == 0) {
            int base = w * 16 + qg * 4;
            dn[base + 0] = dnv[0]; dn[base + 1] = dnv[1];
            dn[base + 2] = dnv[2]; dn[base + 3] = dnv[3];
        }
    }
    __syncthreads();   // D: dn ready; q/k reads done -> Ab may overwrite q region

    // ---- phase 6: normalize in-register, spill Ab bf16 (overlays q region) ----
    {
        float dnj[4];
        #pragma unroll
        for (int jt = 0; jt < 4; jt++) dnj[jt] = dn[jt * 16 + lr];
        #pragma unroll
        for (int jt = 0; jt < 4; jt++)
            #pragma unroll
            for (int r = 0; r < 4; r++) {
                int i = w * 16 + qg * 4 + r, j = jt * 16 + lr;
                *(short*)(tile + i * 128 + (((j >> 3) ^ (i & 7)) << 4) + (j & 7) * 2)
                    = (short)f2bf(sv[jt][r] * dnv[r] * dnj[jt]);
            }
    }
    __syncthreads();   // E: Ab ready

    // ---- phase 7-9: y = w0 v + w1 Av + w2 A^2 v + w3 A^3 v ----
    const float w0c = wv4.x, w1c = wv4.y, w2c = wv4.z, w3c = wv4.w;
    f32x4 y[2];
    #pragma unroll
    for (int ct = 0; ct < 2; ct++)
        #pragma unroll
        for (int r = 0; r < 4; r++) {
            int row = w * 16 + qg * 4 + r;
            int d = ct * 16 + lr;
            unsigned short us = *(unsigned short*)(tile + 16384 + d * 128 + (((row >> 3) ^ (d & 7)) << 4) + (row & 7) * 2);
            y[ct][r] = w0c * bf2f(us);
        }

#define AU_ROUND(SRC, DST, WC, WRITE) {                                                          \
    f32x4 u0 = {0.f,0.f,0.f,0.f}, u1 = {0.f,0.f,0.f,0.f};                                        \
    _Pragma("unroll")                                                                            \
    for (int ks2 = 0; ks2 < 2; ks2++) {                                                          \
        int c = ks2 * 4 + qg;                                                                    \
        bf16x8 af = *(const bf16x8*)(tile + (w * 16 + lr) * 128 + ((c ^ (lr & 7)) << 4));        \
        bf16x8 b0 = *(const bf16x8*)(tile + (SRC) + lr * 128 + ((c ^ (lr & 7)) << 4));           \
        bf16x8 b1 = *(const bf16x8*)(tile + (SRC) + (16 + lr) * 128 + ((c ^ (lr & 7)) << 4));    \
        u0 = __builtin_amdgcn_mfma_f32_16x16x32_bf16(af, b0, u0, 0, 0, 0);                       \
        u1 = __builtin_amdgcn_mfma_f32_16x16x32_bf16(af, b1, u1, 0, 0, 0);                       \
    }                                                                                            \
    y[0] += (WC) * u0; y[1] += (WC) * u1;                                                        \
    if (WRITE) {                                                                                 \
        _Pragma("unroll")                                                                        \
        for (int r = 0; r < 4; r++) {                                                            \
            int i = w * 16 + qg * 4 + r;                                                         \
            *(short*)(tile + (DST) + lr * 128 + (((i >> 3) ^ (lr & 7)) << 4) + (i & 7) * 2) = (short)f2bf(u0[r]); \
            *(short*)(tile + (DST) + (16 + lr) * 128 + (((i >> 3) ^ (lr & 7)) << 4) + (i & 7) * 2) = (short)f2bf(u1[r]); \
        }                                                                                        \
    }                                                                                            \
    __syncthreads();                                                                             \
}
    AU_ROUND(16384, 20480, w1c, 1)   // u1 = A v   -> ua
    AU_ROUND(20480, 24576, w2c, 1)   // u2 = A u1  -> ub
    AU_ROUND(24576, 0,     w3c, 0)   // u3 = A u2
#undef AU_ROUND

    // ---- write hidden bf16 ----
    #pragma unroll
    for (int ct = 0; ct < 2; ct++)
        #pragma unroll
        for (int r = 0; r < 4; r++) {
            int row = w * 16 + qg * 4 + r;
            int col = h * 32 + ct * 16 + lr;
            hid[((size_t)b * 64 + row) * 256 + col] = f2bf(y[ct][r]);
        }
}

// ===================== output projection: 128 x 256 tile, hidden read once =====================
__global__ __launch_bounds__(256) void proj_kernel(
    const unsigned short* __restrict__ hidden,
    const unsigned short* __restrict__ wp,
    const float* __restrict__ bproj,
    float* __restrict__ out)
{
    __shared__ __align__(16) unsigned char atile[65536];
    const int rb = blockIdx.x;
    const int t = threadIdx.x, l = t & 63, w = t >> 6;
    const int lr = l & 15, qg = l >> 4;

    const unsigned short* hb = hidden + (size_t)rb * 128 * 256;
    {
        const int rp = l >> 5, u = l & 31;
        #pragma unroll
        for (int i = 0; i < 16; i++) {
            int row = i * 8 + w * 2 + rp;
            int csrc = (u & 24) | ((u & 7) ^ (row & 7));
            gload_lds16(hb + row * 256 + csrc * 8, atile + (i * 8 + w * 2) * 512);
        }
    }
    float bzv[16];
    #pragma unroll
    for (int ct = 0; ct < 16; ct++) bzv[ct] = bproj[ct * 16 + lr];
    __syncthreads();

    // hoist A fragments: 2 row-tiles x 8 k-steps
    bf16x8 af[2][8];
    #pragma unroll
    for (int rt = 0; rt < 2; rt++) {
        int row = w * 32 + rt * 16 + lr;
        #pragma unroll
        for (int ks = 0; ks < 8; ks++) {
            int c = ks * 4 + qg;
            af[rt][ks] = *(const bf16x8*)(atile + row * 512 + (((c & 24) | ((c & 7) ^ (row & 7))) << 4));
        }
    }

    const uint4* WP = (const uint4*)wp;
    #pragma unroll 2
    for (int ct = 0; ct < 16; ct++) {
        f32x4 a0 = {0.f, 0.f, 0.f, 0.f}, a1 = {0.f, 0.f, 0.f, 0.f};
        #pragma unroll
        for (int ks = 0; ks < 8; ks++) {
            bf16x8 bf = as_bf(WP[(ct * 16 + lr) * 32 + ks * 4 + qg]);
            a0 = __builtin_amdgcn_mfma_f32_16x16x32_bf16(af[0][ks], bf, a0, 0, 0, 0);
            a1 = __builtin_amdgcn_mfma_f32_16x16x32_bf16(af[1][ks], bf, a1, 0, 0, 0);
        }
        int colg = ct * 16 + lr;
        float bz = bzv[ct];
        #pragma unroll
        for (int r = 0; r < 4; r++) {
            int rowg = rb * 128 + w * 32 + qg * 4 + r;
            out[(size_t)rowg * 256 + colg] = a0[r] + bz;
            out[(size_t)(rowg + 16) * 256 + colg] = a1[r] + bz;
        }
    }
}

extern "C" void kernel_launch(void* const* d_in, const int* in_sizes, int n_in,
                              void* d_out, int out_size, void* d_ws, size_t ws_size,
                              hipStream_t stream) {
    const float* x          = (const float*)d_in[0];
    const float* Wq         = (const float*)d_in[1];
    const float* bq         = (const float*)d_in[2];
    const float* Wkv        = (const float*)d_in[3];
    const float* bkv        = (const float*)d_in[4];
    const float* Wgate      = (const float*)d_in[5];
    const float* bgate      = (const float*)d_in[6];
    const float* Wproj      = (const float*)d_in[7];
    const float* bproj      = (const float*)d_in[8];
    const float* bias_table = (const float*)d_in[9];
    const int*   rel_index  = (const int*)d_in[10];
    float* out = (float*)d_out;
    unsigned char* wsb = (unsigned char*)d_ws;

    // ws layout (bytes)
    const size_t HID   = 0;                    // 33,554,432 (hidden bf16)
    const size_t WQo   = 33554432;             // 131072 each
    const size_t WKo   = WQo + 131072;
    const size_t WVo   = WKo + 131072;
    const size_t WPo   = WVo + 131072;
    const size_t BIASo = WPo + 131072;         // 131072 (bsym f32 [8][64][64])
    const size_t WPOLY = BIASo + 131072;       // 131072
    const size_t XBFo  = WPOLY + 131072;       // 33,554,432 (x bf16) — optional
    const int use_xbf  = (ws_size >= XBFo + 33554432ull) ? 1 : 0;

    unsigned short* hid = (unsigned short*)(wsb + HID);
    unsigned short* wq  = (unsigned short*)(wsb + WQo);
    unsigned short* wk  = (unsigned short*)(wsb + WKo);
    unsigned short* wv  = (unsigned short*)(wsb + WVo);
    unsigned short* wp  = (unsigned short*)(wsb + WPo);
    float* bsym  = (float*)(wsb + BIASo);
    float* wpoly = (float*)(wsb + WPOLY);
    unsigned short* xbf = (unsigned short*)(wsb + XBFo);

    prep_kernel<<<dim3(2176), dim3(256), 0, stream>>>(
        x, Wq, Wkv, Wproj, Wgate, bgate, bias_table, rel_index,
        xbf, use_xbf, wq, wk, wv, wp, bsym, wpoly);
    if (use_xbf)
        attn_kernel<true><<<dim3(8192), dim3(256), 0, stream>>>(
            x, xbf, bq, bkv, wq, wk, wv, bsym, wpoly, hid);
    else
        attn_kernel<false><<<dim3(8192), dim3(256), 0, stream>>>(
            x, xbf, bq, bkv, wq, wk, wv, bsym, wpoly, hid);
    proj_kernel<<<dim3(512), dim3(256), 0, stream>>>(hid, wp, bproj, out);
}